// Round 13
// baseline (326.714 us; speedup 1.0000x reference)
//
#include <hip/hip_runtime.h>
#include <hip/hip_bf16.h>
#include <math.h>

// Problem constants (match reference)
constexpr int Bc = 4, Mc = 512, Nc = 1024, Fc = 256;
constexpr int KCc = 16;
constexpr float INFF = 3.0e38f;

typedef __attribute__((ext_vector_type(8))) short short8b;  // 8 bf16 (4 VGPRs)
typedef __attribute__((ext_vector_type(4))) float f32x4;

__device__ __forceinline__ short f2bf(float f) {
  __hip_bfloat16 h = __float2bfloat16(f);
  return *reinterpret_cast<short*>(&h);
}
__device__ __forceinline__ float bf2f(short s) {
  unsigned int u = ((unsigned int)(unsigned short)s) << 16;
  return __uint_as_float(u);
}
__device__ __forceinline__ unsigned long long umin64(unsigned long long a, unsigned long long b) {
  return a < b ? a : b;
}

__device__ __forceinline__ float blk_sum(float v, float* red) {
  int t = threadIdx.x;
  red[t] = v;
  __syncthreads();
  for (int s = 128; s > 0; s >>= 1) {
    if (t < s) red[t] += red[t + s];
    __syncthreads();
  }
  float r = red[0];
  __syncthreads();
  return r;
}

// ---- merged weight relayout: 16 jobs, one kernel ----
struct WSrcs { const float* p[16]; };
__global__ __launch_bounds__(256) void wconv_all(WSrcs s, const float* __restrict__ pw2,
                                                 short* __restrict__ dstbase) {
  const int ofs[16] = {0, 73728, 139264, 204800, 270336, 352256, 434176, 696320,
                       958464, 1024000, 1089536, 1228800, 1359872, 1490944, 1630208, 1761280};
  const int Kt[16]  = {259, 256, 256, 256, 320, 320, 256, 1024, 256, 256, 518, 512, 512, 518, 512, 512};
  const int KTt[16] = {9, 8, 8, 8, 10, 10, 8, 32, 8, 8, 17, 16, 16, 17, 16, 16};
  int gi = blockIdx.x * 256 + threadIdx.x;
  if (gi >= 1892352) return;
  int job = 0;
#pragma unroll
  for (int j2 = 1; j2 < 16; ++j2)
    if (gi >= ofs[j2]) job = j2;
  int i = gi - ofs[job];
  int K = Kt[job], KT = KTt[job];
  int e = i & 7, l = (i >> 3) & 63, q = i >> 9;
  int kk = q % KT, rt = q / KT;
  int r = rt * 16 + (l & 15);
  int k = kk * 32 + (l >> 4) * 8 + e;
  float v;
  if (job == 4)
    v = (k < 256) ? -s.p[4][(size_t)(256 + r) * 256 + k] : pw2[(size_t)r * 64 + (k - 256)];
  else if (job == 5)
    v = (k < 256) ? s.p[5][(size_t)(512 + r) * 256 + k] : pw2[(size_t)r * 64 + (k - 256)];
  else
    v = (k < K) ? s.p[job][(size_t)r * K + k] : 0.f;
  dstbase[gi] = f2bf(v);
}

// ---- generic LDS-tiled transpose: src (B,R,C) -> dst (B,C,R); R,C mult of 64 ----
__global__ __launch_bounds__(256) void transpose_any(const float* __restrict__ src,
                                                     float* __restrict__ dst, int R, int C) {
  __shared__ float tile[64][65];
  int tilesC = C >> 6, tilesR = R >> 6;
  int per = tilesR * tilesC;
  int bid = blockIdx.x;
  int b = bid / per;
  int tl = bid % per;
  int r0 = (tl / tilesC) * 64;
  int c0 = (tl % tilesC) * 64;
  int tx = threadIdx.x & 63, ty = threadIdx.x >> 6;
#pragma unroll
  for (int q = 0; q < 16; ++q) {
    int i = q * 4 + ty;
    tile[i][tx] = src[((size_t)b * R + r0 + i) * C + c0 + tx];
  }
  __syncthreads();
#pragma unroll
  for (int q = 0; q < 16; ++q) {
    int j = q * 4 + ty;
    dst[((size_t)b * C + c0 + j) * R + r0 + tx] = tile[tx][j];
  }
}

// ---- spherical coords of points relative to centroid -> out (B,3,P) ----
__global__ __launch_bounds__(256) void scf_kernel(const float* __restrict__ xyz,
                                                  float* __restrict__ out, int P) {
  __shared__ float red[256];
  int b = blockIdx.x;
  const float* x = xyz + (size_t)b * P * 3;
  float sx = 0.f, sy = 0.f, sz = 0.f;
  for (int i = threadIdx.x; i < P; i += 256) {
    sx += x[3 * i]; sy += x[3 * i + 1]; sz += x[3 * i + 2];
  }
  float mx = blk_sum(sx, red) / (float)P;
  float my = blk_sum(sy, red) / (float)P;
  float mz = blk_sum(sz, red) / (float)P;
  for (int i = threadIdx.x; i < P; i += 256) {
    float a = x[3 * i] - mx, c = x[3 * i + 1] - my, d = x[3 * i + 2] - mz;
    float r = sqrtf(a * a + c * c + d * d + 1e-8f);
    float ct = d / r;
    ct = fminf(1.f, fmaxf(-1.f, ct));
    out[((size_t)b * 3 + 0) * P + i] = r;
    out[((size_t)b * 3 + 1) * P + i] = acosf(ct);
    out[((size_t)b * 3 + 2) * P + i] = atan2f(c, a);
  }
}

// ---- KNN descriptor: ONE WAVE PER POINT, zero barriers ----
template <int P>
__global__ __launch_bounds__(256) void knn_kernel(const float* __restrict__ xyz,
                                                  float* __restrict__ desc) {
  constexpr int E = P / 64;
  int wv = threadIdx.x >> 6, l = threadIdx.x & 63;
  int pt = blockIdx.x * 4 + wv;
  int b = pt / P, i = pt % P;
  const float* x = xyz + (size_t)b * P * 3;
  float xi0 = x[3 * i], xi1 = x[3 * i + 1], xi2 = x[3 * i + 2];
  float d2r[E];
#pragma unroll
  for (int q = 0; q < E; ++q) {
    int j = q * 64 + l;
    float dx = x[3 * j] - xi0, dy = x[3 * j + 1] - xi1, dz = x[3 * j + 2] - xi2;
    d2r[q] = dx * dx + dy * dy + dz * dz;
  }
  for (int round = 0; round < KCc + 1; ++round) {
    unsigned long long k = ~0ULL;
#pragma unroll
    for (int q = 0; q < E; ++q) {
      unsigned long long c =
          ((unsigned long long)__float_as_uint(d2r[q]) << 32) | (unsigned)(q * 64 + l);
      k = umin64(k, c);
    }
#pragma unroll
    for (int m = 1; m < 64; m <<= 1) k = umin64(k, __shfl_xor(k, m));
    int widx = (int)(unsigned)k;
    if (round > 0 && l == 0)
      desc[((size_t)b * P + i) * KCc + (round - 1)] = sqrtf(__uint_as_float((unsigned)(k >> 32)));
    if ((widx & 63) == l) {
      int q = widx >> 6;
#pragma unroll
      for (int qq = 0; qq < E; ++qq)
        if (qq == q) d2r[qq] = INFF;
    }
  }
}

// ---- candidate pruning: ONE WAVE PER POINT, zero barriers ----
__global__ __launch_bounds__(256) void select_kernel(
    const float* __restrict__ tbc, const float* __restrict__ sbc,
    const float* __restrict__ txyz, const float* __restrict__ sxyz,
    const float* __restrict__ sd, const float* __restrict__ td,
    int* __restrict__ idx_s) {
  __shared__ int cand4[4][24];
  int wv = threadIdx.x >> 6, l = threadIdx.x & 63;
  int pt = blockIdx.x * 4 + wv;
  int b = pt / Nc, n = pt % Nc;
  const float* sb = sbc + ((size_t)b * Nc + n) * 9;
  float sreg[9];
#pragma unroll
  for (int c = 0; c < 9; ++c) sreg[c] = sb[c];
  float d2r[8];
#pragma unroll
  for (int q = 0; q < 8; ++q) {
    int m = q * 64 + l;
    const float* tb = tbc + ((size_t)b * Mc + m) * 9;
    float acc = 0.f;
#pragma unroll
    for (int c = 0; c < 9; ++c) { float d = tb[c] - sreg[c]; acc += d * d; }
    d2r[q] = acc;
  }
  for (int round = 0; round < 24; ++round) {
    unsigned long long k = ~0ULL;
#pragma unroll
    for (int q = 0; q < 8; ++q) {
      unsigned long long c =
          ((unsigned long long)__float_as_uint(d2r[q]) << 32) | (unsigned)(q * 64 + l);
      k = umin64(k, c);
    }
#pragma unroll
    for (int m = 1; m < 64; m <<= 1) k = umin64(k, __shfl_xor(k, m));
    int widx = (int)(unsigned)k;
    if (l == 0) cand4[wv][round] = widx;
    if ((widx & 63) == l) {
      int q = widx >> 6;
#pragma unroll
      for (int qq = 0; qq < 8; ++qq)
        if (qq == q) d2r[qq] = INFF;
    }
  }
  if (l == 0) {
    int* cand = cand4[wv];
    const float* sp = sxyz + ((size_t)b * Nc + n) * 3;
    float sx = sp[0], sy = sp[1], sz = sp[2];
    float dv[24];
    for (int t2 = 0; t2 < 24; ++t2) {
      const float* tp = txyz + ((size_t)b * Mc + cand[t2]) * 3;
      float dx = tp[0] - sx, dy = tp[1] - sy, dz = tp[2] - sz;
      dv[t2] = dx * dx + dy * dy + dz * dz;
    }
    int c8[8]; bool used[24];
    for (int t2 = 0; t2 < 24; ++t2) used[t2] = false;
    for (int r = 0; r < 8; ++r) {
      float bv = INFF; int bt = -1, bm = 0x7fffffff;
      for (int t2 = 0; t2 < 24; ++t2) {
        if (used[t2]) continue;
        int m = cand[t2];
        if (bt < 0 || dv[t2] < bv || (dv[t2] == bv && m < bm)) { bv = dv[t2]; bt = t2; bm = m; }
      }
      used[bt] = true; c8[r] = bm;
    }
    const float* sdp = sd + ((size_t)b * Nc + n) * KCc;
    float sdr[16];
    for (int t2 = 0; t2 < 16; ++t2) sdr[t2] = sdp[t2];
    float dscf[8];
    for (int r = 0; r < 8; ++r) {
      const float* tdp = td + ((size_t)b * Mc + c8[r]) * KCc;
      float acc = 0.f;
      for (int t2 = 0; t2 < 16; ++t2) { float d = sdr[t2] - tdp[t2]; acc += d * d; }
      dscf[r] = acc;
    }
    bool u8[8] = {false, false, false, false, false, false, false, false};
    for (int r = 0; r < 4; ++r) {
      float bv = INFF; int bt = -1, bm = 0x7fffffff;
      for (int t2 = 0; t2 < 8; ++t2) {
        if (u8[t2]) continue;
        if (bt < 0 || dscf[t2] < bv || (dscf[t2] == bv && c8[t2] < bm)) { bv = dscf[t2]; bt = t2; bm = c8[t2]; }
      }
      u8[bt] = true;
      idx_s[(((size_t)b * Nc + n) << 2) + r] = bm;
    }
  }
}

// ---- FUSED grouping+MLP+point-transformer, 8 tokens/block, 512 threads ----
// LDS squeezed to 53248 B (3 blocks/CU): 40-real-col B-tiles with phantom col
// reads (garbage confined to discarded output cols 40-47 by MFMA column
// independence); all epilogue writes guarded col<40; vpe spilled to global.
// Byte layout (liveness-audited): MB1@0 MB2@23040 MB3@0 BX@20480 QF@0 KB@8192
// HP@28672 SIM@0 Q04@21120 FEB@29312 FEH@37504 Y2F@0 PC4@49152 RED@51072 MS@51584.
__global__ __launch_bounds__(512, 4) void mlp_attn_kernel(
    const float* __restrict__ sfeatT, const float* __restrict__ tfeatT,
    const float* __restrict__ sscf, const float* __restrict__ tscf,
    const int* __restrict__ idx_s,
    const short* __restrict__ mw1f, const float* __restrict__ mg1, const float* __restrict__ mb1,
    const short* __restrict__ mw2f, const float* __restrict__ mg2, const float* __restrict__ mb2,
    const short* __restrict__ mw3f, const float* __restrict__ mg3, const float* __restrict__ mb3,
    const float* __restrict__ sxyz, const float* __restrict__ sbc,
    const float* __restrict__ txyz, const float* __restrict__ tbc,
    const short* __restrict__ aqf, const short* __restrict__ akpef, const short* __restrict__ avpef,
    const float* __restrict__ pw1, const float* __restrict__ pb1, const float* __restrict__ pb2,
    const short* __restrict__ aw1f, const float* __restrict__ ab1,
    const short* __restrict__ aw2f, const float* __restrict__ ab2,
    const short* __restrict__ fw1f, const float* __restrict__ fg1, const float* __restrict__ fb1,
    const short* __restrict__ fw2f, const float* __restrict__ fb2v,
    short* __restrict__ vpeG,
    float* __restrict__ yout) {
  __shared__ __align__(16) char smem[53248];
  char* mB1 = smem;                 // [40][576]
  char* mB2 = smem + 23040;         // [40][512]
  char* mB3 = smem;                 // [40][512] (alias mB1, dead)
  char* Bx  = smem + 20480;         // [40][640] (alias mB2, dead)
  float* qF = (float*)smem;         // [8][256] f32 (alias mB3, dead)
  char* KB  = smem + 8192;          // [40][512]
  char* HpB = smem + 28672;         // [40][512]
  char* simS = smem;                // [40][528] (alias qF/KB, dead)
  float* q04 = (float*)(smem + 21120); // [8][256] f32
  char* feaB = smem + 29312;        // [16][512] (alias HpB, dead)
  char* feaH = smem + 37504;        // [16][512]
  float* y2F = (float*)smem;        // [8][260] f32 (alias simS, dead)
  float* pc4 = (float*)(smem + 49152); // [40][12] f32
  float* redf = (float*)(smem + 51072); // [128] f32
  int* ms = (int*)(smem + 51584);   // [32] int
  int t = threadIdx.x;
  int tau0 = blockIdx.x * 8;
  int b = tau0 / Nc, n0 = tau0 % Nc;
  int w = t >> 6, l = t & 63, lg = l >> 4, lr = l & 15;
  int h = t >> 8, ch = t & 255;
  short* vpeL = vpeG + (size_t)blockIdx.x * 10240;  // [40][256] bf16 per block
  if (t < 32) ms[t] = idx_s[(((size_t)b * Nc + n0 + (t >> 2)) << 2) + (t & 3)];
  __syncthreads();
  // ---- mlp staging: zero k-pad (real cols only); build mB1 cols<40 ----
  for (int z = t; z < 40 * 29; z += 512) {
    int col = z / 29, k = 259 + z % 29;
    *(short*)(mB1 + ((col * 576 + 2 * k) ^ ((col & 7) << 4))) = 0;
  }
  for (int sj = h; sj < 40; sj += 2) {
    int s = sj / 5, j = sj % 5;
    int n = n0 + s;
    int cx = (sj & 7) << 4;
    if (j == 0) {
      *(short*)(mB1 + ((sj * 576 + 2 * ch) ^ cx)) =
          f2bf(sfeatT[((size_t)b * Nc + n) * 256 + ch]);
      if (ch < 3)
        *(short*)(mB1 + ((sj * 576 + (256 + ch) * 2) ^ cx)) = f2bf(sscf[((size_t)b * 3 + ch) * Nc + n]);
    } else {
      int m = ms[s * 4 + j - 1];
      *(short*)(mB1 + ((sj * 576 + 2 * ch) ^ cx)) =
          f2bf(tfeatT[((size_t)b * Mc + m) * 256 + ch]);
      if (ch < 3)
        *(short*)(mB1 + ((sj * 576 + (256 + ch) * 2) ^ cx)) = f2bf(tscf[((size_t)b * 3 + ch) * Mc + m]);
    }
  }
  __syncthreads();
  // ---- mlp GEMM1: read mB1 (phantom cols OK) -> write mB2 (col<40) ----
  {
    f32x4 acc[2][3];
#pragma unroll
    for (int i = 0; i < 2; ++i)
#pragma unroll
      for (int ct = 0; ct < 3; ++ct) acc[i][ct] = (f32x4){0,0,0,0};
    for (int kk = 0; kk < 9; ++kk) {
      short8b bb[3];
#pragma unroll
      for (int ct = 0; ct < 3; ++ct) {
        int col = ct * 16 + lr;
        bb[ct] = *(const short8b*)(mB1 + ((col * 576 + kk * 64 + lg * 16) ^ ((col & 7) << 4)));
      }
#pragma unroll
      for (int i = 0; i < 2; ++i) {
        short8b a = *(const short8b*)(mw1f + (((size_t)((w * 2 + i) * 9 + kk)) * 64 + l) * 8);
#pragma unroll
        for (int ct = 0; ct < 3; ++ct)
          acc[i][ct] = __builtin_amdgcn_mfma_f32_16x16x32_bf16(a, bb[ct], acc[i][ct], 0, 0, 0);
      }
    }
    __syncthreads();
#pragma unroll
    for (int i = 0; i < 2; ++i) {
      int r0 = (w * 2 + i) * 16 + lg * 4;
      float4 gg = *(const float4*)(mg1 + r0), bs = *(const float4*)(mb1 + r0);
#pragma unroll
      for (int ct = 0; ct < 3; ++ct) {
        int col = ct * 16 + lr;
        if (col < 40) {
          int cx = (col & 7) << 4;
          ushort4 hv;
          hv.x = (unsigned short)f2bf(fmaxf(gg.x * acc[i][ct][0] + bs.x, 0.f));
          hv.y = (unsigned short)f2bf(fmaxf(gg.y * acc[i][ct][1] + bs.y, 0.f));
          hv.z = (unsigned short)f2bf(fmaxf(gg.z * acc[i][ct][2] + bs.z, 0.f));
          hv.w = (unsigned short)f2bf(fmaxf(gg.w * acc[i][ct][3] + bs.w, 0.f));
          *(ushort4*)(mB2 + ((col * 512 + r0 * 2) ^ cx)) = hv;
        }
      }
    }
  }
  __syncthreads();
  // ---- mlp GEMM2: read mB2 -> write mB3 (alias mB1; col<40) ----
  {
    f32x4 acc[2][3];
#pragma unroll
    for (int i = 0; i < 2; ++i)
#pragma unroll
      for (int ct = 0; ct < 3; ++ct) acc[i][ct] = (f32x4){0,0,0,0};
    for (int kk = 0; kk < 8; ++kk) {
      short8b bb[3];
#pragma unroll
      for (int ct = 0; ct < 3; ++ct) {
        int col = ct * 16 + lr;
        bb[ct] = *(const short8b*)(mB2 + ((col * 512 + kk * 64 + lg * 16) ^ ((col & 7) << 4)));
      }
#pragma unroll
      for (int i = 0; i < 2; ++i) {
        short8b a = *(const short8b*)(mw2f + (((size_t)((w * 2 + i) * 8 + kk)) * 64 + l) * 8);
#pragma unroll
        for (int ct = 0; ct < 3; ++ct)
          acc[i][ct] = __builtin_amdgcn_mfma_f32_16x16x32_bf16(a, bb[ct], acc[i][ct], 0, 0, 0);
      }
    }
    __syncthreads();
#pragma unroll
    for (int i = 0; i < 2; ++i) {
      int r0 = (w * 2 + i) * 16 + lg * 4;
      float4 gg = *(const float4*)(mg2 + r0), bs = *(const float4*)(mb2 + r0);
#pragma unroll
      for (int ct = 0; ct < 3; ++ct) {
        int col = ct * 16 + lr;
        if (col < 40) {
          int cx = (col & 7) << 4;
          ushort4 hv;
          hv.x = (unsigned short)f2bf(fmaxf(gg.x * acc[i][ct][0] + bs.x, 0.f));
          hv.y = (unsigned short)f2bf(fmaxf(gg.y * acc[i][ct][1] + bs.y, 0.f));
          hv.z = (unsigned short)f2bf(fmaxf(gg.z * acc[i][ct][2] + bs.z, 0.f));
          hv.w = (unsigned short)f2bf(fmaxf(gg.w * acc[i][ct][3] + bs.w, 0.f));
          *(ushort4*)(mB3 + ((col * 512 + r0 * 2) ^ cx)) = hv;
        }
      }
    }
  }
  __syncthreads();
  // ---- mlp GEMM3: read mB3 -> write Bx (alias mB2; col<40, k<256) ----
  {
    f32x4 acc[2][3];
#pragma unroll
    for (int i = 0; i < 2; ++i)
#pragma unroll
      for (int ct = 0; ct < 3; ++ct) acc[i][ct] = (f32x4){0,0,0,0};
    for (int kk = 0; kk < 8; ++kk) {
      short8b bb[3];
#pragma unroll
      for (int ct = 0; ct < 3; ++ct) {
        int col = ct * 16 + lr;
        bb[ct] = *(const short8b*)(mB3 + ((col * 512 + kk * 64 + lg * 16) ^ ((col & 7) << 4)));
      }
#pragma unroll
      for (int i = 0; i < 2; ++i) {
        short8b a = *(const short8b*)(mw3f + (((size_t)((w * 2 + i) * 8 + kk)) * 64 + l) * 8);
#pragma unroll
        for (int ct = 0; ct < 3; ++ct)
          acc[i][ct] = __builtin_amdgcn_mfma_f32_16x16x32_bf16(a, bb[ct], acc[i][ct], 0, 0, 0);
      }
    }
    __syncthreads();  // all mB3 (+phantom) reads done before Bx writes
#pragma unroll
    for (int i = 0; i < 2; ++i) {
      int r0 = (w * 2 + i) * 16 + lg * 4;
      float4 gg = *(const float4*)(mg3 + r0), bs = *(const float4*)(mb3 + r0);
#pragma unroll
      for (int ct = 0; ct < 3; ++ct) {
        int col = ct * 16 + lr;
        if (col < 40) {
          int cx = (col & 7) << 4;
          ushort4 hv;
          hv.x = (unsigned short)f2bf(fmaxf(gg.x * acc[i][ct][0] + bs.x, 0.f));
          hv.y = (unsigned short)f2bf(fmaxf(gg.y * acc[i][ct][1] + bs.y, 0.f));
          hv.z = (unsigned short)f2bf(fmaxf(gg.z * acc[i][ct][2] + bs.z, 0.f));
          hv.w = (unsigned short)f2bf(fmaxf(gg.w * acc[i][ct][3] + bs.w, 0.f));
          *(ushort4*)(Bx + ((col * 640 + r0 * 2) ^ cx)) = hv;
        }
      }
    }
  }
  __syncthreads();
  // ---- pc4 load ----
  if (t < 40) {
    int s = t / 5, k = t % 5;
    int n = n0 + s;
    float* pd = pc4 + t * 12;
    if (k == 0) {
      for (int c = 0; c < 3; ++c) pd[c] = sxyz[((size_t)b * Nc + n) * 3 + c];
      for (int c = 0; c < 9; ++c) pd[3 + c] = sbc[((size_t)b * Nc + n) * 9 + c];
    } else {
      int m = idx_s[(((size_t)b * Nc + n) << 2) + (k - 1)];
      for (int c = 0; c < 3; ++c) pd[c] = txyz[((size_t)b * Mc + m) * 3 + c];
      for (int c = 0; c < 9; ++c) pd[3 + c] = tbc[((size_t)b * Mc + m) * 9 + c];
    }
  }
  __syncthreads();
  // ---- P1: pe hidden (relu) -> Bx k = 256+h ----
  for (int it = t; it < 2560; it += 512) {
    int sj = it >> 6, hh = it & 63;
    int s = sj / 5;
    float acc = pb1[hh];
    const float* wv = pw1 + hh * 12;
    const float* p0 = pc4 + (s * 5) * 12;
    const float* pj = pc4 + sj * 12;
#pragma unroll
    for (int p = 0; p < 12; ++p) acc += wv[p] * (p0[p] - pj[p]);
    *(short*)(Bx + ((sj * 640 + 512 + 2 * hh) ^ ((sj & 7) << 4))) = f2bf(fmaxf(acc, 0.f));
  }
  __syncthreads();
  // ---- P2a: q GEMM (K=256) -> qF (alias mB3, dead) ----
  {
    f32x4 qA[2][3];
#pragma unroll
    for (int i = 0; i < 2; ++i)
#pragma unroll
      for (int ct = 0; ct < 3; ++ct) qA[i][ct] = (f32x4){0,0,0,0};
    for (int kk = 0; kk < 8; ++kk) {
      short8b bq[3];
#pragma unroll
      for (int ct = 0; ct < 3; ++ct) {
        int col = ct * 16 + lr;
        bq[ct] = *(const short8b*)(Bx + ((col * 640 + kk * 64 + lg * 16) ^ ((col & 7) << 4)));
      }
#pragma unroll
      for (int i = 0; i < 2; ++i) {
        short8b a = *(const short8b*)(aqf + (((size_t)((w * 2 + i) * 8 + kk)) * 64 + l) * 8);
#pragma unroll
        for (int ct = 0; ct < 3; ++ct)
          qA[i][ct] = __builtin_amdgcn_mfma_f32_16x16x32_bf16(a, bq[ct], qA[i][ct], 0, 0, 0);
      }
    }
#pragma unroll
    for (int i = 0; i < 2; ++i) {
      int r0 = (w * 2 + i) * 16 + lg * 4;
#pragma unroll
      for (int ct = 0; ct < 3; ++ct) {
        int col = ct * 16 + lr;
        if (col < 40 && col % 5 == 0)
          *(f32x4*)(qF + (col / 5) * 256 + r0) = qA[i][ct];
      }
    }
  }
  // ---- P2b: (-k+pe) and (v+pe) GEMMs, K=320 ----
  f32x4 sA[2][3], vA[2][3];
#pragma unroll
  for (int i = 0; i < 2; ++i)
#pragma unroll
    for (int ct = 0; ct < 3; ++ct) { sA[i][ct] = (f32x4){0,0,0,0}; vA[i][ct] = (f32x4){0,0,0,0}; }
  for (int kk = 0; kk < 10; ++kk) {
    short8b bb[3];
#pragma unroll
    for (int ct = 0; ct < 3; ++ct) {
      int col = ct * 16 + lr;
      bb[ct] = *(const short8b*)(Bx + ((col * 640 + kk * 64 + lg * 16) ^ ((col & 7) << 4)));
    }
#pragma unroll
    for (int i = 0; i < 2; ++i) {
      short8b ak = *(const short8b*)(akpef + (((size_t)((w * 2 + i) * 10 + kk)) * 64 + l) * 8);
      short8b av = *(const short8b*)(avpef + (((size_t)((w * 2 + i) * 10 + kk)) * 64 + l) * 8);
#pragma unroll
      for (int ct = 0; ct < 3; ++ct) {
        sA[i][ct] = __builtin_amdgcn_mfma_f32_16x16x32_bf16(ak, bb[ct], sA[i][ct], 0, 0, 0);
        vA[i][ct] = __builtin_amdgcn_mfma_f32_16x16x32_bf16(av, bb[ct], vA[i][ct], 0, 0, 0);
      }
    }
  }
  __syncthreads();
  // ---- P3: KB = bf16(q + sA + pb2) (col<40); vpe -> global ----
#pragma unroll
  for (int i = 0; i < 2; ++i) {
    int r0 = (w * 2 + i) * 16 + lg * 4;
    float4 pb = *(const float4*)(pb2 + r0);
#pragma unroll
    for (int ct = 0; ct < 3; ++ct) {
      int col = ct * 16 + lr;
      if (col < 40) {
        int cx = (col & 7) << 4;
        int s = col / 5;
        f32x4 qv = *(const f32x4*)(qF + s * 256 + r0);
        ushort4 kv, vv;
        kv.x = (unsigned short)f2bf(qv[0] + sA[i][ct][0] + pb.x);
        kv.y = (unsigned short)f2bf(qv[1] + sA[i][ct][1] + pb.y);
        kv.z = (unsigned short)f2bf(qv[2] + sA[i][ct][2] + pb.z);
        kv.w = (unsigned short)f2bf(qv[3] + sA[i][ct][3] + pb.w);
        vv.x = (unsigned short)f2bf(vA[i][ct][0] + pb.x);
        vv.y = (unsigned short)f2bf(vA[i][ct][1] + pb.y);
        vv.z = (unsigned short)f2bf(vA[i][ct][2] + pb.z);
        vv.w = (unsigned short)f2bf(vA[i][ct][3] + pb.w);
        *(ushort4*)(KB + ((col * 512 + r0 * 2) ^ cx)) = kv;
        *(ushort4*)(vpeL + col * 256 + r0) = vv;
      }
    }
  }
  __syncthreads();
  // ---- P4: amlp via MFMA: 4 panels of 256 hidden rows ----
  f32x4 sacc[2][3];
#pragma unroll
  for (int i = 0; i < 2; ++i)
#pragma unroll
    for (int ct = 0; ct < 3; ++ct) sacc[i][ct] = (f32x4){0,0,0,0};
  for (int p = 0; p < 4; ++p) {
    f32x4 hacc[2][3];
#pragma unroll
    for (int i = 0; i < 2; ++i)
#pragma unroll
      for (int ct = 0; ct < 3; ++ct) hacc[i][ct] = (f32x4){0,0,0,0};
    for (int kk = 0; kk < 8; ++kk) {
      short8b bb[3];
#pragma unroll
      for (int ct = 0; ct < 3; ++ct) {
        int col = ct * 16 + lr;
        bb[ct] = *(const short8b*)(KB + ((col * 512 + kk * 64 + lg * 16) ^ ((col & 7) << 4)));
      }
#pragma unroll
      for (int i = 0; i < 2; ++i) {
        int rtg = p * 16 + w * 2 + i;
        short8b a = *(const short8b*)(aw1f + (((size_t)(rtg * 8 + kk)) * 64 + l) * 8);
#pragma unroll
        for (int ct = 0; ct < 3; ++ct)
          hacc[i][ct] = __builtin_amdgcn_mfma_f32_16x16x32_bf16(a, bb[ct], hacc[i][ct], 0, 0, 0);
      }
    }
    __syncthreads();  // KB (+phantom=HpB-region) reads done before HpB writes
#pragma unroll
    for (int i = 0; i < 2; ++i) {
      int r0l = (w * 2 + i) * 16 + lg * 4;
      float4 bias = *(const float4*)(ab1 + p * 256 + r0l);
#pragma unroll
      for (int ct = 0; ct < 3; ++ct) {
        int col = ct * 16 + lr;
        if (col < 40) {
          int cx = (col & 7) << 4;
          ushort4 hv;
          hv.x = (unsigned short)f2bf(fmaxf(hacc[i][ct][0] + bias.x, 0.f));
          hv.y = (unsigned short)f2bf(fmaxf(hacc[i][ct][1] + bias.y, 0.f));
          hv.z = (unsigned short)f2bf(fmaxf(hacc[i][ct][2] + bias.z, 0.f));
          hv.w = (unsigned short)f2bf(fmaxf(hacc[i][ct][3] + bias.w, 0.f));
          *(ushort4*)(HpB + ((col * 512 + r0l * 2) ^ cx)) = hv;
        }
      }
    }
    __syncthreads();
    for (int kk = 0; kk < 8; ++kk) {
      short8b bb[3];
#pragma unroll
      for (int ct = 0; ct < 3; ++ct) {
        int col = ct * 16 + lr;
        bb[ct] = *(const short8b*)(HpB + ((col * 512 + kk * 64 + lg * 16) ^ ((col & 7) << 4)));
      }
      int kkg = p * 8 + kk;
#pragma unroll
      for (int i = 0; i < 2; ++i) {
        short8b a = *(const short8b*)(aw2f + (((size_t)((w * 2 + i) * 32 + kkg)) * 64 + l) * 8);
#pragma unroll
        for (int ct = 0; ct < 3; ++ct)
          sacc[i][ct] = __builtin_amdgcn_mfma_f32_16x16x32_bf16(a, bb[ct], sacc[i][ct], 0, 0, 0);
      }
    }
    __syncthreads();
  }
  // ---- P5: sim (+ab2) -> simS bf16 (cols < 40; alias dead qF/KB) ----
#pragma unroll
  for (int i = 0; i < 2; ++i) {
    int r0 = (w * 2 + i) * 16 + lg * 4;
    float4 bias = *(const float4*)(ab2 + r0);
#pragma unroll
    for (int ct = 0; ct < 3; ++ct) {
      int col = ct * 16 + lr;
      if (col < 40) {
        ushort4 hv;
        hv.x = (unsigned short)f2bf(sacc[i][ct][0] + bias.x);
        hv.y = (unsigned short)f2bf(sacc[i][ct][1] + bias.y);
        hv.z = (unsigned short)f2bf(sacc[i][ct][2] + bias.z);
        hv.w = (unsigned short)f2bf(sacc[i][ct][3] + bias.w);
        *(ushort4*)(simS + col * 528 + r0 * 2) = hv;
      }
    }
  }
  __syncthreads();
  // ---- P6: softmax + aggregate (vpe from global) + residual + inorm -> q04 ----
  float ffv[4];
#pragma unroll
  for (int si = 0; si < 4; ++si) {
    int s = h * 4 + si;
    float sv[5], vp[5];
#pragma unroll
    for (int j = 0; j < 5; ++j) {
      int sj = s * 5 + j;
      sv[j] = bf2f(*(const short*)(simS + sj * 528 + 2 * ch));
      vp[j] = bf2f(vpeL[sj * 256 + ch]);
    }
    float mx = sv[0];
#pragma unroll
    for (int j = 1; j < 5; ++j) mx = fmaxf(mx, sv[j]);
    float ssum = 0.f;
#pragma unroll
    for (int j = 0; j < 5; ++j) { sv[j] = expf(sv[j] - mx); ssum += sv[j]; }
    float inv = 1.f / ssum;
    float agg = 0.f;
#pragma unroll
    for (int j = 0; j < 5; ++j) agg += (sv[j] * inv) * vp[j];
    ffv[si] = agg + sfeatT[((size_t)b * Nc + (n0 + s)) * 256 + ch];
  }
  {
    float rv[8];
#pragma unroll
    for (int si = 0; si < 4; ++si) { rv[si] = ffv[si]; rv[4 + si] = ffv[si] * ffv[si]; }
#pragma unroll
    for (int m = 1; m < 64; m <<= 1)
#pragma unroll
      for (int i2 = 0; i2 < 8; ++i2) rv[i2] += __shfl_xor(rv[i2], m);
    if ((t & 63) == 0)
#pragma unroll
      for (int i2 = 0; i2 < 8; ++i2) redf[w * 8 + i2] = rv[i2];
    __syncthreads();
#pragma unroll
    for (int si = 0; si < 4; ++si) {
      int s = h * 4 + si;
      float S = 0.f, Q = 0.f;
#pragma unroll
      for (int q2 = 0; q2 < 4; ++q2) {
        S += redf[(h * 4 + q2) * 8 + si];
        Q += redf[(h * 4 + q2) * 8 + 4 + si];
      }
      float mu = S * (1.f / 256.f);
      float var = Q * (1.f / 256.f) - mu * mu;
      q04[s * 256 + ch] = (ffv[si] - mu) / sqrtf(var + 1e-5f);
    }
  }
  __syncthreads();
  // ---- P7: feaB cols 0-7 from q04; zero cols 8-15 ----
  for (int z = t; z < 16 * 256; z += 512) {
    int col = z >> 8, k = z & 255;
    short val = (col < 8) ? f2bf(q04[col * 256 + k]) : (short)0;
    *(short*)(feaB + ((col * 512 + 2 * k) ^ ((col & 7) << 4))) = val;
  }
  __syncthreads();
  // ---- P8: fea layer 1 -> feaH ----
  {
    f32x4 acc[2];
#pragma unroll
    for (int i = 0; i < 2; ++i) acc[i] = (f32x4){0,0,0,0};
    for (int kk = 0; kk < 8; ++kk) {
      short8b b0 = *(const short8b*)(feaB + ((lr * 512 + kk * 64 + lg * 16) ^ ((lr & 7) << 4)));
#pragma unroll
      for (int i = 0; i < 2; ++i) {
        short8b a = *(const short8b*)(fw1f + (((size_t)((w * 2 + i) * 8 + kk)) * 64 + l) * 8);
        acc[i] = __builtin_amdgcn_mfma_f32_16x16x32_bf16(a, b0, acc[i], 0, 0, 0);
      }
    }
#pragma unroll
    for (int i = 0; i < 2; ++i) {
      int r0 = (w * 2 + i) * 16 + lg * 4;
      float4 gg = *(const float4*)(fg1 + r0), bs = *(const float4*)(fb1 + r0);
      int cx = (lr & 7) << 4;
      ushort4 hv;
      hv.x = (unsigned short)f2bf(fmaxf(gg.x * acc[i][0] + bs.x, 0.f));
      hv.y = (unsigned short)f2bf(fmaxf(gg.y * acc[i][1] + bs.y, 0.f));
      hv.z = (unsigned short)f2bf(fmaxf(gg.z * acc[i][2] + bs.z, 0.f));
      hv.w = (unsigned short)f2bf(fmaxf(gg.w * acc[i][3] + bs.w, 0.f));
      *(ushort4*)(feaH + ((lr * 512 + r0 * 2) ^ cx)) = hv;
    }
  }
  __syncthreads();
  // ---- P9: fea layer 2 -> y2F cols 0-7 (alias dead simS) ----
  {
    f32x4 acc[2];
#pragma unroll
    for (int i = 0; i < 2; ++i) acc[i] = (f32x4){0,0,0,0};
    for (int kk = 0; kk < 8; ++kk) {
      short8b b0 = *(const short8b*)(feaH + ((lr * 512 + kk * 64 + lg * 16) ^ ((lr & 7) << 4)));
#pragma unroll
      for (int i = 0; i < 2; ++i) {
        short8b a = *(const short8b*)(fw2f + (((size_t)((w * 2 + i) * 8 + kk)) * 64 + l) * 8);
        acc[i] = __builtin_amdgcn_mfma_f32_16x16x32_bf16(a, b0, acc[i], 0, 0, 0);
      }
    }
    __syncthreads();  // all simS reads finished (P6); y2F aliases simS
#pragma unroll
    for (int i = 0; i < 2; ++i) {
      if (lr < 8) {
        int r0 = (w * 2 + i) * 16 + lg * 4;
        float4 bs = *(const float4*)(fb2v + r0);
        float4 v;
        v.x = acc[i][0] + bs.x; v.y = acc[i][1] + bs.y;
        v.z = acc[i][2] + bs.z; v.w = acc[i][3] + bs.w;
        *(float4*)(y2F + lr * 260 + r0) = v;
      }
    }
  }
  __syncthreads();
  // ---- P10: z = y2 + ffn; instance norm; out ----
  {
    float zv[4];
#pragma unroll
    for (int si = 0; si < 4; ++si) {
      int s = h * 4 + si;
      zv[si] = y2F[s * 260 + ch] + q04[s * 256 + ch];
    }
    float rv[8];
#pragma unroll
    for (int si = 0; si < 4; ++si) { rv[si] = zv[si]; rv[4 + si] = zv[si] * zv[si]; }
#pragma unroll
    for (int m = 1; m < 64; m <<= 1)
#pragma unroll
      for (int i2 = 0; i2 < 8; ++i2) rv[i2] += __shfl_xor(rv[i2], m);
    if ((t & 63) == 0)
#pragma unroll
      for (int i2 = 0; i2 < 8; ++i2) redf[w * 8 + i2] = rv[i2];
    __syncthreads();
#pragma unroll
    for (int si = 0; si < 4; ++si) {
      int s = h * 4 + si;
      float S = 0.f, Q = 0.f;
#pragma unroll
      for (int q2 = 0; q2 < 4; ++q2) {
        S += redf[(h * 4 + q2) * 8 + si];
        Q += redf[(h * 4 + q2) * 8 + 4 + si];
      }
      float mu = S * (1.f / 256.f);
      float var = Q * (1.f / 256.f) - mu * mu;
      yout[((size_t)(tau0 + s)) * 256 + ch] = (zv[si] - mu) / sqrtf(var + 1e-5f);
    }
  }
}

// ---- PointSIFT octant-NN: ONE WAVE PER POINT, zero barriers ----
__global__ __launch_bounds__(256) void sift_idx_kernel(const float* __restrict__ sxyz,
                                                       int* __restrict__ sidx) {
  int wv = threadIdx.x >> 6, l = threadIdx.x & 63;
  int pt = blockIdx.x * 4 + wv;
  int b = pt / Nc, i = pt % Nc;
  const float* x = sxyz + (size_t)b * Nc * 3;
  float xi0 = x[3 * i], xi1 = x[3 * i + 1], xi2 = x[3 * i + 2];
  unsigned long long k8[8];
#pragma unroll
  for (int o = 0; o < 8; ++o) k8[o] = ~0ULL;
  for (int q = 0; q < 16; ++q) {
    int j = q * 64 + l;
    float dx = x[3 * j] - xi0, dy = x[3 * j + 1] - xi1, dz = x[3 * j + 2] - xi2;
    float d2 = dx * dx + dy * dy + dz * dz;
    bool ok = (d2 <= 0.25f) && (d2 > 0.f);
    int oc = (dx > 0.f ? 4 : 0) + (dy > 0.f ? 2 : 0) + (dz > 0.f ? 1 : 0);
    unsigned long long c = ((unsigned long long)__float_as_uint(d2) << 32) | (unsigned)j;
#pragma unroll
    for (int o = 0; o < 8; ++o) {
      unsigned long long cc = (ok && oc == o) ? c : ~0ULL;
      k8[o] = umin64(k8[o], cc);
    }
  }
#pragma unroll
  for (int m = 1; m < 64; m <<= 1)
#pragma unroll
    for (int o = 0; o < 8; ++o) k8[o] = umin64(k8[o], __shfl_xor(k8[o], m));
  if (l < 8) {
    unsigned long long r = ~0ULL;
#pragma unroll
    for (int o = 0; o < 8; ++o)
      if (l == o) r = k8[o];
    int j = (r == ~0ULL) ? i : (int)(unsigned)r;
    sidx[(((size_t)b * Nc + i) << 3) + l] = j;
  }
}

// ---- fused PointSIFT OE: 3 (1,2)-convs via MFMA, 8 points/block, 512 threads ----
__global__ __launch_bounds__(512, 4) void sift_oe_kernel(
    const float* __restrict__ sxyz, const int* __restrict__ sidx,
    const float* __restrict__ yin,
    const short* __restrict__ w1f, const float* __restrict__ g1, const float* __restrict__ b1,
    const short* __restrict__ w2f, const float* __restrict__ g2, const float* __restrict__ b2,
    const short* __restrict__ w3f, const float* __restrict__ g3, const float* __restrict__ b3,
    float* __restrict__ yout) {
  __shared__ __align__(16) char smem[51200];
  char* B1 = smem;
  char* B2 = smem + 34816;
  char* B3 = smem;
  __shared__ int js[8][8];
  int t = threadIdx.x;
  int i0 = blockIdx.x * 8;
  int b = i0 / Nc, nb = i0 % Nc;
  int h = t >> 8, ch = t & 255;
  if (t < 64) js[t >> 3][t & 7] = sidx[(((size_t)b * Nc + nb + (t >> 3)) << 3) + (t & 7)];
  for (int z = t; z < 32 * 26; z += 512) {
    int col = z / 26, k = 518 + z % 26;
    *(short*)(B1 + ((col * 1088 + 2 * k) ^ ((col & 7) << 4))) = 0;
  }
  __syncthreads();
  for (int si = 0; si < 4; ++si) {
    int s = h * 4 + si;
    int ii = nb + s;
#pragma unroll
    for (int p = 0; p < 4; ++p) {
      int ja = js[s][2 * p], jb = js[s][2 * p + 1];
      int col = s * 4 + p; int cx = (col & 7) << 4;
      float va = yin[((size_t)b * Nc + ja) * 256 + ch];
      float vb = yin[((size_t)b * Nc + jb) * 256 + ch];
      unsigned int packed = (unsigned int)(unsigned short)f2bf(va) |
                            ((unsigned int)(unsigned short)f2bf(vb) << 16);
      *(unsigned int*)(B1 + ((col * 1088 + 12 + 4 * ch) ^ cx)) = packed;
      if (ch < 3) {
        float base = sxyz[((size_t)b * Nc + ii) * 3 + ch];
        float ga = sxyz[((size_t)b * Nc + ja) * 3 + ch] - base;
        float gb = sxyz[((size_t)b * Nc + jb) * 3 + ch] - base;
        unsigned int pg = (unsigned int)(unsigned short)f2bf(ga) |
                          ((unsigned int)(unsigned short)f2bf(gb) << 16);
        *(unsigned int*)(B1 + ((col * 1088 + 4 * ch) ^ cx)) = pg;
      }
    }
  }
  __syncthreads();
  int l = t & 63, w = t >> 6, lg = l >> 4, lr = l & 15;
  {
    f32x4 acc[2][2];
#pragma unroll
    for (int i = 0; i < 2; ++i) { acc[i][0] = (f32x4){0,0,0,0}; acc[i][1] = (f32x4){0,0,0,0}; }
    for (int kk = 0; kk < 17; ++kk) {
      short8b b0[2];
#pragma unroll
      for (int ct = 0; ct < 2; ++ct) {
        int col = ct * 16 + lr;
        b0[ct] = *(const short8b*)(B1 + ((col * 1088 + kk * 64 + lg * 16) ^ ((col & 7) << 4)));
      }
#pragma unroll
      for (int i = 0; i < 2; ++i) {
        short8b a = *(const short8b*)(w1f + (((size_t)((w * 2 + i) * 17 + kk)) * 64 + l) * 8);
#pragma unroll
        for (int ct = 0; ct < 2; ++ct)
          acc[i][ct] = __builtin_amdgcn_mfma_f32_16x16x32_bf16(a, b0[ct], acc[i][ct], 0, 0, 0);
      }
    }
    __syncthreads();
#pragma unroll
    for (int i = 0; i < 2; ++i) {
      int r0 = (w * 2 + i) * 16 + lg * 4;
      float4 gg = *(const float4*)(g1 + r0), bs = *(const float4*)(b1 + r0);
#pragma unroll
      for (int ct = 0; ct < 2; ++ct) {
        int col = ct * 16 + lr;
        int s = col >> 2, p = col & 3, p2 = p >> 1, tp = p & 1;
        int col2 = s * 2 + p2; int cx2 = (col2 & 7) << 4;
        *(short*)(B2 + ((col2 * 1024 + (2 * r0 + tp) * 2) ^ cx2)) =
            f2bf(fmaxf(gg.x * acc[i][ct][0] + bs.x, 0.f));
        *(short*)(B2 + ((col2 * 1024 + (2 * (r0 + 1) + tp) * 2) ^ cx2)) =
            f2bf(fmaxf(gg.y * acc[i][ct][1] + bs.y, 0.f));
        *(short*)(B2 + ((col2 * 1024 + (2 * (r0 + 2) + tp) * 2) ^ cx2)) =
            f2bf(fmaxf(gg.z * acc[i][ct][2] + bs.z, 0.f));
        *(short*)(B2 + ((col2 * 1024 + (2 * (r0 + 3) + tp) * 2) ^ cx2)) =
            f2bf(fmaxf(gg.w * acc[i][ct][3] + bs.w, 0.f));
      }
    }
  }
  __syncthreads();
  {
    f32x4 acc[2];
#pragma unroll
    for (int i = 0; i < 2; ++i) acc[i] = (f32x4){0,0,0,0};
    for (int kk = 0; kk < 16; ++kk) {
      short8b b0 = *(const short8b*)(B2 + ((lr * 1024 + kk * 64 + lg * 16) ^ ((lr & 7) << 4)));
#pragma unroll
      for (int i = 0; i < 2; ++i) {
        short8b a = *(const short8b*)(w2f + (((size_t)((w * 2 + i) * 16 + kk)) * 64 + l) * 8);
        acc[i] = __builtin_amdgcn_mfma_f32_16x16x32_bf16(a, b0, acc[i], 0, 0, 0);
      }
    }
    __syncthreads();
    int s = lr >> 1, tp = lr & 1;
    int col3 = s; int cx3 = (col3 & 7) << 4;
#pragma unroll
    for (int i = 0; i < 2; ++i) {
      int r0 = (w * 2 + i) * 16 + lg * 4;
      float4 gg = *(const float4*)(g2 + r0), bs = *(const float4*)(b2 + r0);
      *(short*)(B3 + ((col3 * 1024 + (2 * r0 + tp) * 2) ^ cx3)) =
          f2bf(fmaxf(gg.x * acc[i][0] + bs.x, 0.f));
      *(short*)(B3 + ((col3 * 1024 + (2 * (r0 + 1) + tp) * 2) ^ cx3)) =
          f2bf(fmaxf(gg.y * acc[i][1] + bs.y, 0.f));
      *(short*)(B3 + ((col3 * 1024 + (2 * (r0 + 2) + tp) * 2) ^ cx3)) =
          f2bf(fmaxf(gg.z * acc[i][2] + bs.z, 0.f));
      *(short*)(B3 + ((col3 * 1024 + (2 * (r0 + 3) + tp) * 2) ^ cx3)) =
          f2bf(fmaxf(gg.w * acc[i][3] + bs.w, 0.f));
    }
  }
  __syncthreads();
  {
    f32x4 acc[2];
#pragma unroll
    for (int i = 0; i < 2; ++i) acc[i] = (f32x4){0,0,0,0};
    for (int kk = 0; kk < 16; ++kk) {
      short8b b0 = *(const short8b*)(B3 + ((lr * 1024 + kk * 64 + lg * 16) ^ ((lr & 7) << 4)));
#pragma unroll
      for (int i = 0; i < 2; ++i) {
        short8b a = *(const short8b*)(w3f + (((size_t)((w * 2 + i) * 16 + kk)) * 64 + l) * 8);
        acc[i] = __builtin_amdgcn_mfma_f32_16x16x32_bf16(a, b0, acc[i], 0, 0, 0);
      }
    }
#pragma unroll
    for (int i = 0; i < 2; ++i) {
      if (lr < 8) {
        int s = lr;
        int r0 = (w * 2 + i) * 16 + lg * 4;
        float4 gg = *(const float4*)(g3 + r0), bs = *(const float4*)(b3 + r0);
        float4 yv = *(const float4*)(yin + ((size_t)(i0 + s)) * 256 + r0);
        float4 ov;
        ov.x = yv.x + fmaxf(gg.x * acc[i][0] + bs.x, 0.f);
        ov.y = yv.y + fmaxf(gg.y * acc[i][1] + bs.y, 0.f);
        ov.z = yv.z + fmaxf(gg.z * acc[i][2] + bs.z, 0.f);
        ov.w = yv.w + fmaxf(gg.w * acc[i][3] + bs.w, 0.f);
        *(float4*)(yout + ((size_t)(i0 + s)) * 256 + r0) = ov;
      }
    }
  }
}

extern "C" void kernel_launch(void* const* d_in, const int* in_sizes, int n_in,
                              void* d_out, int out_size, void* d_ws, size_t ws_size,
                              hipStream_t stream) {
  (void)in_sizes; (void)n_in; (void)out_size; (void)ws_size;
  const float* tfeat = (const float*)d_in[0];
  const float* sfeat = (const float*)d_in[1];
  const float* txyz  = (const float*)d_in[2];
  const float* sxyz  = (const float*)d_in[3];
  const float* tbc   = (const float*)d_in[4];
  const float* sbc   = (const float*)d_in[5];
  const float* mw1 = (const float*)d_in[6];
  const float* mg1 = (const float*)d_in[7];
  const float* mb1 = (const float*)d_in[8];
  const float* mw2 = (const float*)d_in[9];
  const float* mg2 = (const float*)d_in[10];
  const float* mb2 = (const float*)d_in[11];
  const float* mw3 = (const float*)d_in[12];
  const float* mg3 = (const float*)d_in[13];
  const float* mb3 = (const float*)d_in[14];
  const float* fw1 = (const float*)d_in[15];
  const float* fg1 = (const float*)d_in[16];
  const float* fb1 = (const float*)d_in[17];
  const float* fw2 = (const float*)d_in[18];
  const float* fb2 = (const float*)d_in[19];
  const float* wqkv = (const float*)d_in[20];
  const float* pw1 = (const float*)d_in[21];
  const float* pb1 = (const float*)d_in[22];
  const float* pw2 = (const float*)d_in[23];
  const float* pb2 = (const float*)d_in[24];
  const float* aw1 = (const float*)d_in[25];
  const float* ab1 = (const float*)d_in[26];
  const float* aw2 = (const float*)d_in[27];
  const float* ab2 = (const float*)d_in[28];
  const float* o1w1 = (const float*)d_in[29];
  const float* o1g1 = (const float*)d_in[30];
  const float* o1b1 = (const float*)d_in[31];
  const float* o1w2 = (const float*)d_in[32];
  const float* o1g2 = (const float*)d_in[33];
  const float* o1b2 = (const float*)d_in[34];
  const float* o1w3 = (const float*)d_in[35];
  const float* o1g3 = (const float*)d_in[36];
  const float* o1b3 = (const float*)d_in[37];
  const float* o2w1 = (const float*)d_in[38];
  const float* o2g1 = (const float*)d_in[39];
  const float* o2b1 = (const float*)d_in[40];
  const float* o2w2 = (const float*)d_in[41];
  const float* o2g2 = (const float*)d_in[42];
  const float* o2b2 = (const float*)d_in[43];
  const float* o2w3 = (const float*)d_in[44];
  const float* o2g3 = (const float*)d_in[45];
  const float* o2b3 = (const float*)d_in[46];

  // workspace layout (R12 + vpeG aliasing the mlp-era scratch, free during mlp_attn)
  float* ws = (float*)d_ws;
  float* sd   = ws;
  float* td   = sd + 65536;
  float* sscf = td + 32768;
  float* tscf = sscf + 12288;
  int*   idxs = (int*)(tscf + 6144);
  int*   sidx = idxs + 16384;
  float* yws  = (float*)(sidx + 32768);
  short* sb   = (short*)(yws + 1048576);
  short* mw1f  = sb + 5242880;
  short* mw2f  = mw1f + 73728;
  short* mw3f  = mw2f + 65536;
  short* aqf   = mw3f + 65536;
  short* akpef = aqf + 65536;
  short* avpef = akpef + 81920;
  short* aw1f  = avpef + 81920;
  short* aw2f  = aw1f + 262144;
  short* fw1f  = aw2f + 262144;
  short* fw2f  = fw1f + 65536;
  short* o1w1f = fw2f + 65536;
  short* o1w2f = o1w1f + 139264;
  short* o1w3f = o1w2f + 131072;
  short* o2w1f = o1w3f + 131072;
  short* o2w2f = o2w1f + 139264;
  short* o2w3f = o2w2f + 131072;
  float* sfeatT = (float*)(sb + 7135232);   // B*N*F = 1,048,576 f32
  float* tfeatT = sfeatT + 1048576;         // B*M*F = 524,288 f32
  short* vpeG  = sb;                        // 512 blocks x 10240 bf16 (live only in mlp_attn)
  float* ybuf2 = (float*)sb;                // sift ping-pong (after mlp_attn; vpeG dead)

  WSrcs srcs;
  srcs.p[0] = mw1;  srcs.p[1] = mw2;  srcs.p[2] = mw3;  srcs.p[3] = wqkv;
  srcs.p[4] = wqkv; srcs.p[5] = wqkv; srcs.p[6] = aw1;  srcs.p[7] = aw2;
  srcs.p[8] = fw1;  srcs.p[9] = fw2;  srcs.p[10] = o1w1; srcs.p[11] = o1w2;
  srcs.p[12] = o1w3; srcs.p[13] = o2w1; srcs.p[14] = o2w2; srcs.p[15] = o2w3;
  wconv_all<<<7392, 256, 0, stream>>>(srcs, pw2, mw1f);

  // pre-transpose inputs to token-major for coalesced gathers
  transpose_any<<<Bc * 4 * 16, 256, 0, stream>>>(sfeat, sfeatT, Fc, Nc);
  transpose_any<<<Bc * 4 * 8, 256, 0, stream>>>(tfeat, tfeatT, Fc, Mc);

  scf_kernel<<<Bc, 256, 0, stream>>>(sxyz, sscf, Nc);
  scf_kernel<<<Bc, 256, 0, stream>>>(txyz, tscf, Mc);
  knn_kernel<Nc><<<Bc * Nc / 4, 256, 0, stream>>>(sxyz, sd);
  knn_kernel<Mc><<<Bc * Mc / 4, 256, 0, stream>>>(txyz, td);
  select_kernel<<<Bc * Nc / 4, 256, 0, stream>>>(tbc, sbc, txyz, sxyz, sd, td, idxs);
  mlp_attn_kernel<<<Bc * Nc / 8, 512, 0, stream>>>(
      sfeatT, tfeatT, sscf, tscf, idxs,
      mw1f, mg1, mb1, mw2f, mg2, mb2, mw3f, mg3, mb3,
      sxyz, sbc, txyz, tbc,
      aqf, akpef, avpef, pw1, pb1, pb2,
      aw1f, ab1, aw2f, ab2,
      fw1f, fg1, fb1, fw2f, fb2, vpeG, yws);
  sift_idx_kernel<<<Bc * Nc / 4, 256, 0, stream>>>(sxyz, sidx);
  sift_oe_kernel<<<Bc * Nc / 8, 512, 0, stream>>>(sxyz, sidx, yws,
                                                  o1w1f, o1g1, o1b1, o1w2f, o1g2, o1b2,
                                                  o1w3f, o1g3, o1b3, ybuf2);
  sift_oe_kernel<<<Bc * Nc / 8, 512, 0, stream>>>(sxyz, sidx, ybuf2,
                                                  o2w1f, o2g1, o2b1, o2w2f, o2g2, o2b2,
                                                  o2w3f, o2g3, o2b3, yws);
  transpose_any<<<Bc * 16 * 4, 256, 0, stream>>>(yws, (float*)d_out, Nc, Fc);
}

// Round 14
// 314.887 us; speedup vs baseline: 1.0376x; 1.0376x over previous
//
#include <hip/hip_runtime.h>
#include <hip/hip_bf16.h>
#include <math.h>

// Problem constants (match reference)
constexpr int Bc = 4, Mc = 512, Nc = 1024, Fc = 256;
constexpr int KCc = 16;
constexpr float INFF = 3.0e38f;

typedef __attribute__((ext_vector_type(8))) short short8b;  // 8 bf16 (4 VGPRs)
typedef __attribute__((ext_vector_type(4))) float f32x4;

__device__ __forceinline__ short f2bf(float f) {
  __hip_bfloat16 h = __float2bfloat16(f);
  return *reinterpret_cast<short*>(&h);
}
__device__ __forceinline__ float bf2f(short s) {
  unsigned int u = ((unsigned int)(unsigned short)s) << 16;
  return __uint_as_float(u);
}
__device__ __forceinline__ unsigned long long umin64(unsigned long long a, unsigned long long b) {
  return a < b ? a : b;
}

__device__ __forceinline__ float blk_sum(float v, float* red) {
  int t = threadIdx.x;
  red[t] = v;
  __syncthreads();
  for (int s = 128; s > 0; s >>= 1) {
    if (t < s) red[t] += red[t + s];
    __syncthreads();
  }
  float r = red[0];
  __syncthreads();
  return r;
}

// ---- merged weight relayout: 16 jobs, one kernel ----
struct WSrcs { const float* p[16]; };
__global__ __launch_bounds__(256) void wconv_all(WSrcs s, const float* __restrict__ pw2,
                                                 short* __restrict__ dstbase) {
  const int ofs[16] = {0, 73728, 139264, 204800, 270336, 352256, 434176, 696320,
                       958464, 1024000, 1089536, 1228800, 1359872, 1490944, 1630208, 1761280};
  const int Kt[16]  = {259, 256, 256, 256, 320, 320, 256, 1024, 256, 256, 518, 512, 512, 518, 512, 512};
  const int KTt[16] = {9, 8, 8, 8, 10, 10, 8, 32, 8, 8, 17, 16, 16, 17, 16, 16};
  int gi = blockIdx.x * 256 + threadIdx.x;
  if (gi >= 1892352) return;
  int job = 0;
#pragma unroll
  for (int j2 = 1; j2 < 16; ++j2)
    if (gi >= ofs[j2]) job = j2;
  int i = gi - ofs[job];
  int K = Kt[job], KT = KTt[job];
  int e = i & 7, l = (i >> 3) & 63, q = i >> 9;
  int kk = q % KT, rt = q / KT;
  int r = rt * 16 + (l & 15);
  int k = kk * 32 + (l >> 4) * 8 + e;
  float v;
  if (job == 4)
    v = (k < 256) ? -s.p[4][(size_t)(256 + r) * 256 + k] : pw2[(size_t)r * 64 + (k - 256)];
  else if (job == 5)
    v = (k < 256) ? s.p[5][(size_t)(512 + r) * 256 + k] : pw2[(size_t)r * 64 + (k - 256)];
  else
    v = (k < K) ? s.p[job][(size_t)r * K + k] : 0.f;
  dstbase[gi] = f2bf(v);
}

// ---- spherical coords of points relative to centroid -> out (B,3,P) ----
__global__ __launch_bounds__(256) void scf_kernel(const float* __restrict__ xyz,
                                                  float* __restrict__ out, int P) {
  __shared__ float red[256];
  int b = blockIdx.x;
  const float* x = xyz + (size_t)b * P * 3;
  float sx = 0.f, sy = 0.f, sz = 0.f;
  for (int i = threadIdx.x; i < P; i += 256) {
    sx += x[3 * i]; sy += x[3 * i + 1]; sz += x[3 * i + 2];
  }
  float mx = blk_sum(sx, red) / (float)P;
  float my = blk_sum(sy, red) / (float)P;
  float mz = blk_sum(sz, red) / (float)P;
  for (int i = threadIdx.x; i < P; i += 256) {
    float a = x[3 * i] - mx, c = x[3 * i + 1] - my, d = x[3 * i + 2] - mz;
    float r = sqrtf(a * a + c * c + d * d + 1e-8f);
    float ct = d / r;
    ct = fminf(1.f, fmaxf(-1.f, ct));
    out[((size_t)b * 3 + 0) * P + i] = r;
    out[((size_t)b * 3 + 1) * P + i] = acosf(ct);
    out[((size_t)b * 3 + 2) * P + i] = atan2f(c, a);
  }
}

// ---- KNN descriptor: ONE WAVE PER POINT, zero barriers ----
template <int P>
__global__ __launch_bounds__(256) void knn_kernel(const float* __restrict__ xyz,
                                                  float* __restrict__ desc) {
  constexpr int E = P / 64;
  int wv = threadIdx.x >> 6, l = threadIdx.x & 63;
  int pt = blockIdx.x * 4 + wv;
  int b = pt / P, i = pt % P;
  const float* x = xyz + (size_t)b * P * 3;
  float xi0 = x[3 * i], xi1 = x[3 * i + 1], xi2 = x[3 * i + 2];
  float d2r[E];
#pragma unroll
  for (int q = 0; q < E; ++q) {
    int j = q * 64 + l;
    float dx = x[3 * j] - xi0, dy = x[3 * j + 1] - xi1, dz = x[3 * j + 2] - xi2;
    d2r[q] = dx * dx + dy * dy + dz * dz;
  }
  for (int round = 0; round < KCc + 1; ++round) {
    unsigned long long k = ~0ULL;
#pragma unroll
    for (int q = 0; q < E; ++q) {
      unsigned long long c =
          ((unsigned long long)__float_as_uint(d2r[q]) << 32) | (unsigned)(q * 64 + l);
      k = umin64(k, c);
    }
#pragma unroll
    for (int m = 1; m < 64; m <<= 1) k = umin64(k, __shfl_xor(k, m));
    int widx = (int)(unsigned)k;
    if (round > 0 && l == 0)
      desc[((size_t)b * P + i) * KCc + (round - 1)] = sqrtf(__uint_as_float((unsigned)(k >> 32)));
    if ((widx & 63) == l) {
      int q = widx >> 6;
#pragma unroll
      for (int qq = 0; qq < E; ++qq)
        if (qq == q) d2r[qq] = INFF;
    }
  }
}

// ---- candidate pruning: ONE WAVE PER POINT, zero barriers ----
__global__ __launch_bounds__(256) void select_kernel(
    const float* __restrict__ tbc, const float* __restrict__ sbc,
    const float* __restrict__ txyz, const float* __restrict__ sxyz,
    const float* __restrict__ sd, const float* __restrict__ td,
    int* __restrict__ idx_s) {
  __shared__ int cand4[4][24];
  int wv = threadIdx.x >> 6, l = threadIdx.x & 63;
  int pt = blockIdx.x * 4 + wv;
  int b = pt / Nc, n = pt % Nc;
  const float* sb = sbc + ((size_t)b * Nc + n) * 9;
  float sreg[9];
#pragma unroll
  for (int c = 0; c < 9; ++c) sreg[c] = sb[c];
  float d2r[8];
#pragma unroll
  for (int q = 0; q < 8; ++q) {
    int m = q * 64 + l;
    const float* tb = tbc + ((size_t)b * Mc + m) * 9;
    float acc = 0.f;
#pragma unroll
    for (int c = 0; c < 9; ++c) { float d = tb[c] - sreg[c]; acc += d * d; }
    d2r[q] = acc;
  }
  for (int round = 0; round < 24; ++round) {
    unsigned long long k = ~0ULL;
#pragma unroll
    for (int q = 0; q < 8; ++q) {
      unsigned long long c =
          ((unsigned long long)__float_as_uint(d2r[q]) << 32) | (unsigned)(q * 64 + l);
      k = umin64(k, c);
    }
#pragma unroll
    for (int m = 1; m < 64; m <<= 1) k = umin64(k, __shfl_xor(k, m));
    int widx = (int)(unsigned)k;
    if (l == 0) cand4[wv][round] = widx;
    if ((widx & 63) == l) {
      int q = widx >> 6;
#pragma unroll
      for (int qq = 0; qq < 8; ++qq)
        if (qq == q) d2r[qq] = INFF;
    }
  }
  if (l == 0) {
    int* cand = cand4[wv];
    const float* sp = sxyz + ((size_t)b * Nc + n) * 3;
    float sx = sp[0], sy = sp[1], sz = sp[2];
    float dv[24];
    for (int t2 = 0; t2 < 24; ++t2) {
      const float* tp = txyz + ((size_t)b * Mc + cand[t2]) * 3;
      float dx = tp[0] - sx, dy = tp[1] - sy, dz = tp[2] - sz;
      dv[t2] = dx * dx + dy * dy + dz * dz;
    }
    int c8[8]; bool used[24];
    for (int t2 = 0; t2 < 24; ++t2) used[t2] = false;
    for (int r = 0; r < 8; ++r) {
      float bv = INFF; int bt = -1, bm = 0x7fffffff;
      for (int t2 = 0; t2 < 24; ++t2) {
        if (used[t2]) continue;
        int m = cand[t2];
        if (bt < 0 || dv[t2] < bv || (dv[t2] == bv && m < bm)) { bv = dv[t2]; bt = t2; bm = m; }
      }
      used[bt] = true; c8[r] = bm;
    }
    const float* sdp = sd + ((size_t)b * Nc + n) * KCc;
    float sdr[16];
    for (int t2 = 0; t2 < 16; ++t2) sdr[t2] = sdp[t2];
    float dscf[8];
    for (int r = 0; r < 8; ++r) {
      const float* tdp = td + ((size_t)b * Mc + c8[r]) * KCc;
      float acc = 0.f;
      for (int t2 = 0; t2 < 16; ++t2) { float d = sdr[t2] - tdp[t2]; acc += d * d; }
      dscf[r] = acc;
    }
    bool u8[8] = {false, false, false, false, false, false, false, false};
    for (int r = 0; r < 4; ++r) {
      float bv = INFF; int bt = -1, bm = 0x7fffffff;
      for (int t2 = 0; t2 < 8; ++t2) {
        if (u8[t2]) continue;
        if (bt < 0 || dscf[t2] < bv || (dscf[t2] == bv && c8[t2] < bm)) { bv = dscf[t2]; bt = t2; bm = c8[t2]; }
      }
      u8[bt] = true;
      idx_s[(((size_t)b * Nc + n) << 2) + r] = bm;
    }
  }
}

// ---- FUSED grouping+MLP+point-transformer, 8 tokens/block, 512 threads ----
// mlp GEMM3 writes its bf16 output straight into attn's Bx LDS tile (no hbufS).
__global__ __launch_bounds__(512, 4) void mlp_attn_kernel(
    const float* __restrict__ sfeat, const float* __restrict__ tfeat,
    const float* __restrict__ sscf, const float* __restrict__ tscf,
    const int* __restrict__ idx_s,
    const short* __restrict__ mw1f, const float* __restrict__ mg1, const float* __restrict__ mb1,
    const short* __restrict__ mw2f, const float* __restrict__ mg2, const float* __restrict__ mb2,
    const short* __restrict__ mw3f, const float* __restrict__ mg3, const float* __restrict__ mb3,
    const float* __restrict__ sxyz, const float* __restrict__ sbc,
    const float* __restrict__ txyz, const float* __restrict__ tbc,
    const short* __restrict__ aqf, const short* __restrict__ akpef, const short* __restrict__ avpef,
    const float* __restrict__ pw1, const float* __restrict__ pb1, const float* __restrict__ pb2,
    const short* __restrict__ aw1f, const float* __restrict__ ab1,
    const short* __restrict__ aw2f, const float* __restrict__ ab2,
    const short* __restrict__ fw1f, const float* __restrict__ fg1, const float* __restrict__ fb1,
    const short* __restrict__ fw2f, const float* __restrict__ fb2v,
    float* __restrict__ yout) {
  __shared__ __align__(16) char smem[79872];
  // mlp overlays (all dead before attn phases use the same bytes):
  char* mB1 = smem;                        // [48][576] = 27648
  char* mB2 = smem + 27648;                // [48][512] ends 52224
  char* mB3 = smem + 52224;                // [48][512] ends 76800
  // attn overlays (layout identical to R10 attn):
  char* Bx   = smem;                       // [48][640] (x written by mlp GEMM3)
  char* vpeB = smem;
  char* feaB = smem;
  char* feaH = smem + 8192;
  float* y2F = (float*)(smem + 16384);
  char* KB   = smem + 30720;
  char* simS = smem + 30720;
  char* HpB  = smem + 55296;
  float* qF  = (float*)(smem + 55296);
  float* q04 = (float*)(smem + 55296);
  float* redf = (float*)(smem + 63488);
  float* pc4 = (float*)(smem + 64000);     // loaded AFTER mlp (region overlaps mB3)
  __shared__ int ms[32];
  int t = threadIdx.x;
  int tau0 = blockIdx.x * 8;
  int b = tau0 / Nc, n0 = tau0 % Nc;
  int w = t >> 6, l = t & 63, lg = l >> 4, lr = l & 15;
  int h = t >> 8, ch = t & 255;
  if (t < 32) ms[t] = idx_s[(((size_t)b * Nc + n0 + (t >> 2)) << 2) + (t & 3)];
  __syncthreads();
  // ---- mlp staging: zero k-pad + cols 40-47; build mB1 cols<40 ----
  for (int z = t; z < 48 * 29; z += 512) {
    int col = z / 29, k = 259 + z % 29;
    *(short*)(mB1 + ((col * 576 + 2 * k) ^ ((col & 7) << 4))) = 0;
  }
  for (int z = t; z < 8 * 259; z += 512) {
    int col = 40 + z / 259, k = z % 259;
    *(short*)(mB1 + ((col * 576 + 2 * k) ^ ((col & 7) << 4))) = 0;
  }
  for (int sj = h; sj < 40; sj += 2) {
    int s = sj / 5, j = sj % 5;
    int n = n0 + s;
    int cx = (sj & 7) << 4;
    if (j == 0) {
      *(short*)(mB1 + ((sj * 576 + 2 * ch) ^ cx)) = f2bf(sfeat[((size_t)b * Fc + ch) * Nc + n]);
      if (ch < 3)
        *(short*)(mB1 + ((sj * 576 + (256 + ch) * 2) ^ cx)) = f2bf(sscf[((size_t)b * 3 + ch) * Nc + n]);
    } else {
      int m = ms[s * 4 + j - 1];
      *(short*)(mB1 + ((sj * 576 + 2 * ch) ^ cx)) = f2bf(tfeat[((size_t)b * Fc + ch) * Mc + m]);
      if (ch < 3)
        *(short*)(mB1 + ((sj * 576 + (256 + ch) * 2) ^ cx)) = f2bf(tscf[((size_t)b * 3 + ch) * Mc + m]);
    }
  }
  __syncthreads();
  // ---- mlp GEMM1: 256 x K288 (KT=9) -> mB2 ----
  {
    f32x4 acc[2][3];
#pragma unroll
    for (int i = 0; i < 2; ++i)
#pragma unroll
      for (int ct = 0; ct < 3; ++ct) acc[i][ct] = (f32x4){0,0,0,0};
    for (int kk = 0; kk < 9; ++kk) {
      short8b bb[3];
#pragma unroll
      for (int ct = 0; ct < 3; ++ct) {
        int col = ct * 16 + lr;
        bb[ct] = *(const short8b*)(mB1 + ((col * 576 + kk * 64 + lg * 16) ^ ((col & 7) << 4)));
      }
#pragma unroll
      for (int i = 0; i < 2; ++i) {
        short8b a = *(const short8b*)(mw1f + (((size_t)((w * 2 + i) * 9 + kk)) * 64 + l) * 8);
#pragma unroll
        for (int ct = 0; ct < 3; ++ct)
          acc[i][ct] = __builtin_amdgcn_mfma_f32_16x16x32_bf16(a, bb[ct], acc[i][ct], 0, 0, 0);
      }
    }
    __syncthreads();
#pragma unroll
    for (int i = 0; i < 2; ++i) {
      int r0 = (w * 2 + i) * 16 + lg * 4;
      float4 gg = *(const float4*)(mg1 + r0), bs = *(const float4*)(mb1 + r0);
#pragma unroll
      for (int ct = 0; ct < 3; ++ct) {
        int col = ct * 16 + lr; int cx = (col & 7) << 4;
        ushort4 hv;
        hv.x = (unsigned short)f2bf(fmaxf(gg.x * acc[i][ct][0] + bs.x, 0.f));
        hv.y = (unsigned short)f2bf(fmaxf(gg.y * acc[i][ct][1] + bs.y, 0.f));
        hv.z = (unsigned short)f2bf(fmaxf(gg.z * acc[i][ct][2] + bs.z, 0.f));
        hv.w = (unsigned short)f2bf(fmaxf(gg.w * acc[i][ct][3] + bs.w, 0.f));
        *(ushort4*)(mB2 + ((col * 512 + r0 * 2) ^ cx)) = hv;
      }
    }
  }
  __syncthreads();
  // ---- mlp GEMM2: 256 x 256 -> mB3 ----
  {
    f32x4 acc[2][3];
#pragma unroll
    for (int i = 0; i < 2; ++i)
#pragma unroll
      for (int ct = 0; ct < 3; ++ct) acc[i][ct] = (f32x4){0,0,0,0};
    for (int kk = 0; kk < 8; ++kk) {
      short8b bb[3];
#pragma unroll
      for (int ct = 0; ct < 3; ++ct) {
        int col = ct * 16 + lr;
        bb[ct] = *(const short8b*)(mB2 + ((col * 512 + kk * 64 + lg * 16) ^ ((col & 7) << 4)));
      }
#pragma unroll
      for (int i = 0; i < 2; ++i) {
        short8b a = *(const short8b*)(mw2f + (((size_t)((w * 2 + i) * 8 + kk)) * 64 + l) * 8);
#pragma unroll
        for (int ct = 0; ct < 3; ++ct)
          acc[i][ct] = __builtin_amdgcn_mfma_f32_16x16x32_bf16(a, bb[ct], acc[i][ct], 0, 0, 0);
      }
    }
    __syncthreads();
#pragma unroll
    for (int i = 0; i < 2; ++i) {
      int r0 = (w * 2 + i) * 16 + lg * 4;
      float4 gg = *(const float4*)(mg2 + r0), bs = *(const float4*)(mb2 + r0);
#pragma unroll
      for (int ct = 0; ct < 3; ++ct) {
        int col = ct * 16 + lr; int cx = (col & 7) << 4;
        ushort4 hv;
        hv.x = (unsigned short)f2bf(fmaxf(gg.x * acc[i][ct][0] + bs.x, 0.f));
        hv.y = (unsigned short)f2bf(fmaxf(gg.y * acc[i][ct][1] + bs.y, 0.f));
        hv.z = (unsigned short)f2bf(fmaxf(gg.z * acc[i][ct][2] + bs.z, 0.f));
        hv.w = (unsigned short)f2bf(fmaxf(gg.w * acc[i][ct][3] + bs.w, 0.f));
        *(ushort4*)(mB3 + ((col * 512 + r0 * 2) ^ cx)) = hv;
      }
    }
  }
  __syncthreads();
  // ---- mlp GEMM3: 256 x 256 -> Bx x-region (cols<40, k<256); zero Bx cols 40-47 ----
  {
    f32x4 acc[2][3];
#pragma unroll
    for (int i = 0; i < 2; ++i)
#pragma unroll
      for (int ct = 0; ct < 3; ++ct) acc[i][ct] = (f32x4){0,0,0,0};
    for (int kk = 0; kk < 8; ++kk) {
      short8b bb[3];
#pragma unroll
      for (int ct = 0; ct < 3; ++ct) {
        int col = ct * 16 + lr;
        bb[ct] = *(const short8b*)(mB3 + ((col * 512 + kk * 64 + lg * 16) ^ ((col & 7) << 4)));
      }
#pragma unroll
      for (int i = 0; i < 2; ++i) {
        short8b a = *(const short8b*)(mw3f + (((size_t)((w * 2 + i) * 8 + kk)) * 64 + l) * 8);
#pragma unroll
        for (int ct = 0; ct < 3; ++ct)
          acc[i][ct] = __builtin_amdgcn_mfma_f32_16x16x32_bf16(a, bb[ct], acc[i][ct], 0, 0, 0);
      }
    }
    __syncthreads();  // all mB3 reads done; mB1/mB2 regions now fully dead
#pragma unroll
    for (int i = 0; i < 2; ++i) {
      int r0 = (w * 2 + i) * 16 + lg * 4;
      float4 gg = *(const float4*)(mg3 + r0), bs = *(const float4*)(mb3 + r0);
#pragma unroll
      for (int ct = 0; ct < 3; ++ct) {
        int col = ct * 16 + lr;
        if (col < 40) {
          int cx = (col & 7) << 4;
          ushort4 hv;
          hv.x = (unsigned short)f2bf(fmaxf(gg.x * acc[i][ct][0] + bs.x, 0.f));
          hv.y = (unsigned short)f2bf(fmaxf(gg.y * acc[i][ct][1] + bs.y, 0.f));
          hv.z = (unsigned short)f2bf(fmaxf(gg.z * acc[i][ct][2] + bs.z, 0.f));
          hv.w = (unsigned short)f2bf(fmaxf(gg.w * acc[i][ct][3] + bs.w, 0.f));
          *(ushort4*)(Bx + ((col * 640 + r0 * 2) ^ cx)) = hv;
        }
      }
    }
    // NaN-safety: zero Bx cols 40..47 (full k<320)
    for (int z = t; z < 2560; z += 512) {
      int col = 40 + z / 320, k = z % 320;
      *(short*)(Bx + ((col * 640 + 2 * k) ^ ((col & 7) << 4))) = 0;
    }
  }
  __syncthreads();
  // ---- pc4 load (moved here: region overlapped mB3) ----
  if (t < 40) {
    int s = t / 5, k = t % 5;
    int n = n0 + s;
    float* pd = pc4 + t * 12;
    if (k == 0) {
      for (int c = 0; c < 3; ++c) pd[c] = sxyz[((size_t)b * Nc + n) * 3 + c];
      for (int c = 0; c < 9; ++c) pd[3 + c] = sbc[((size_t)b * Nc + n) * 9 + c];
    } else {
      int m = idx_s[(((size_t)b * Nc + n) << 2) + (k - 1)];
      for (int c = 0; c < 3; ++c) pd[c] = txyz[((size_t)b * Mc + m) * 3 + c];
      for (int c = 0; c < 9; ++c) pd[3 + c] = tbc[((size_t)b * Mc + m) * 9 + c];
    }
  }
  __syncthreads();
  // ---- P1: pe hidden (relu) -> Bx k = 256+h ----
  for (int it = t; it < 2560; it += 512) {
    int sj = it >> 6, hh = it & 63;
    int s = sj / 5;
    float acc = pb1[hh];
    const float* wv = pw1 + hh * 12;
    const float* p0 = pc4 + (s * 5) * 12;
    const float* pj = pc4 + sj * 12;
#pragma unroll
    for (int p = 0; p < 12; ++p) acc += wv[p] * (p0[p] - pj[p]);
    *(short*)(Bx + ((sj * 640 + 512 + 2 * hh) ^ ((sj & 7) << 4))) = f2bf(fmaxf(acc, 0.f));
  }
  __syncthreads();
  // ---- P2a: q GEMM (K=256) -> qF ----
  {
    f32x4 qA[2][3];
#pragma unroll
    for (int i = 0; i < 2; ++i)
#pragma unroll
      for (int ct = 0; ct < 3; ++ct) qA[i][ct] = (f32x4){0,0,0,0};
    for (int kk = 0; kk < 8; ++kk) {
      short8b bq[3];
#pragma unroll
      for (int ct = 0; ct < 3; ++ct) {
        int col = ct * 16 + lr;
        bq[ct] = *(const short8b*)(Bx + ((col * 640 + kk * 64 + lg * 16) ^ ((col & 7) << 4)));
      }
#pragma unroll
      for (int i = 0; i < 2; ++i) {
        short8b a = *(const short8b*)(aqf + (((size_t)((w * 2 + i) * 8 + kk)) * 64 + l) * 8);
#pragma unroll
        for (int ct = 0; ct < 3; ++ct)
          qA[i][ct] = __builtin_amdgcn_mfma_f32_16x16x32_bf16(a, bq[ct], qA[i][ct], 0, 0, 0);
      }
    }
#pragma unroll
    for (int i = 0; i < 2; ++i) {
      int r0 = (w * 2 + i) * 16 + lg * 4;
#pragma unroll
      for (int ct = 0; ct < 3; ++ct) {
        int col = ct * 16 + lr;
        if (col < 40 && col % 5 == 0)
          *(f32x4*)(qF + (col / 5) * 256 + r0) = qA[i][ct];
      }
    }
  }
  // ---- P2b: (-k+pe) and (v+pe) GEMMs, K=320 ----
  f32x4 sA[2][3], vA[2][3];
#pragma unroll
  for (int i = 0; i < 2; ++i)
#pragma unroll
    for (int ct = 0; ct < 3; ++ct) { sA[i][ct] = (f32x4){0,0,0,0}; vA[i][ct] = (f32x4){0,0,0,0}; }
  for (int kk = 0; kk < 10; ++kk) {
    short8b bb[3];
#pragma unroll
    for (int ct = 0; ct < 3; ++ct) {
      int col = ct * 16 + lr;
      bb[ct] = *(const short8b*)(Bx + ((col * 640 + kk * 64 + lg * 16) ^ ((col & 7) << 4)));
    }
#pragma unroll
    for (int i = 0; i < 2; ++i) {
      short8b ak = *(const short8b*)(akpef + (((size_t)((w * 2 + i) * 10 + kk)) * 64 + l) * 8);
      short8b av = *(const short8b*)(avpef + (((size_t)((w * 2 + i) * 10 + kk)) * 64 + l) * 8);
#pragma unroll
      for (int ct = 0; ct < 3; ++ct) {
        sA[i][ct] = __builtin_amdgcn_mfma_f32_16x16x32_bf16(ak, bb[ct], sA[i][ct], 0, 0, 0);
        vA[i][ct] = __builtin_amdgcn_mfma_f32_16x16x32_bf16(av, bb[ct], vA[i][ct], 0, 0, 0);
      }
    }
  }
  __syncthreads();
  // ---- P3: KB = bf16(q + sA + pb2); vpeB = bf16(vA + pb2) ----
#pragma unroll
  for (int i = 0; i < 2; ++i) {
    int r0 = (w * 2 + i) * 16 + lg * 4;
    float4 pb = *(const float4*)(pb2 + r0);
#pragma unroll
    for (int ct = 0; ct < 3; ++ct) {
      int col = ct * 16 + lr; int cx = (col & 7) << 4;
      if (col < 40) {
        int s = col / 5;
        f32x4 qv = *(const f32x4*)(qF + s * 256 + r0);
        ushort4 kv, vv;
        kv.x = (unsigned short)f2bf(qv[0] + sA[i][ct][0] + pb.x);
        kv.y = (unsigned short)f2bf(qv[1] + sA[i][ct][1] + pb.y);
        kv.z = (unsigned short)f2bf(qv[2] + sA[i][ct][2] + pb.z);
        kv.w = (unsigned short)f2bf(qv[3] + sA[i][ct][3] + pb.w);
        vv.x = (unsigned short)f2bf(vA[i][ct][0] + pb.x);
        vv.y = (unsigned short)f2bf(vA[i][ct][1] + pb.y);
        vv.z = (unsigned short)f2bf(vA[i][ct][2] + pb.z);
        vv.w = (unsigned short)f2bf(vA[i][ct][3] + pb.w);
        *(ushort4*)(KB + ((col * 512 + r0 * 2) ^ cx)) = kv;
        *(ushort4*)(vpeB + ((col * 512 + r0 * 2) ^ cx)) = vv;
      } else {
        ushort4 zz; zz.x = zz.y = zz.z = zz.w = 0;
        *(ushort4*)(KB + ((col * 512 + r0 * 2) ^ cx)) = zz;
      }
    }
  }
  __syncthreads();
  // ---- P4: amlp via MFMA: 4 panels of 256 hidden rows ----
  f32x4 sacc[2][3];
#pragma unroll
  for (int i = 0; i < 2; ++i)
#pragma unroll
    for (int ct = 0; ct < 3; ++ct) sacc[i][ct] = (f32x4){0,0,0,0};
  for (int p = 0; p < 4; ++p) {
    f32x4 hacc[2][3];
#pragma unroll
    for (int i = 0; i < 2; ++i)
#pragma unroll
      for (int ct = 0; ct < 3; ++ct) hacc[i][ct] = (f32x4){0,0,0,0};
    for (int kk = 0; kk < 8; ++kk) {
      short8b bb[3];
#pragma unroll
      for (int ct = 0; ct < 3; ++ct) {
        int col = ct * 16 + lr;
        bb[ct] = *(const short8b*)(KB + ((col * 512 + kk * 64 + lg * 16) ^ ((col & 7) << 4)));
      }
#pragma unroll
      for (int i = 0; i < 2; ++i) {
        int rtg = p * 16 + w * 2 + i;
        short8b a = *(const short8b*)(aw1f + (((size_t)(rtg * 8 + kk)) * 64 + l) * 8);
#pragma unroll
        for (int ct = 0; ct < 3; ++ct)
          hacc[i][ct] = __builtin_amdgcn_mfma_f32_16x16x32_bf16(a, bb[ct], hacc[i][ct], 0, 0, 0);
      }
    }
#pragma unroll
    for (int i = 0; i < 2; ++i) {
      int r0l = (w * 2 + i) * 16 + lg * 4;
      float4 bias = *(const float4*)(ab1 + p * 256 + r0l);
#pragma unroll
      for (int ct = 0; ct < 3; ++ct) {
        int col = ct * 16 + lr; int cx = (col & 7) << 4;
        ushort4 hv;
        hv.x = (unsigned short)f2bf(fmaxf(hacc[i][ct][0] + bias.x, 0.f));
        hv.y = (unsigned short)f2bf(fmaxf(hacc[i][ct][1] + bias.y, 0.f));
        hv.z = (unsigned short)f2bf(fmaxf(hacc[i][ct][2] + bias.z, 0.f));
        hv.w = (unsigned short)f2bf(fmaxf(hacc[i][ct][3] + bias.w, 0.f));
        *(ushort4*)(HpB + ((col * 512 + r0l * 2) ^ cx)) = hv;
      }
    }
    __syncthreads();
    for (int kk = 0; kk < 8; ++kk) {
      short8b bb[3];
#pragma unroll
      for (int ct = 0; ct < 3; ++ct) {
        int col = ct * 16 + lr;
        bb[ct] = *(const short8b*)(HpB + ((col * 512 + kk * 64 + lg * 16) ^ ((col & 7) << 4)));
      }
      int kkg = p * 8 + kk;
#pragma unroll
      for (int i = 0; i < 2; ++i) {
        short8b a = *(const short8b*)(aw2f + (((size_t)((w * 2 + i) * 32 + kkg)) * 64 + l) * 8);
#pragma unroll
        for (int ct = 0; ct < 3; ++ct)
          sacc[i][ct] = __builtin_amdgcn_mfma_f32_16x16x32_bf16(a, bb[ct], sacc[i][ct], 0, 0, 0);
      }
    }
    __syncthreads();
  }
  // ---- P5: sim (+ab2) -> simS bf16 (cols < 40) ----
#pragma unroll
  for (int i = 0; i < 2; ++i) {
    int r0 = (w * 2 + i) * 16 + lg * 4;
    float4 bias = *(const float4*)(ab2 + r0);
#pragma unroll
    for (int ct = 0; ct < 3; ++ct) {
      int col = ct * 16 + lr;
      if (col < 40) {
        ushort4 hv;
        hv.x = (unsigned short)f2bf(sacc[i][ct][0] + bias.x);
        hv.y = (unsigned short)f2bf(sacc[i][ct][1] + bias.y);
        hv.z = (unsigned short)f2bf(sacc[i][ct][2] + bias.z);
        hv.w = (unsigned short)f2bf(sacc[i][ct][3] + bias.w);
        *(ushort4*)(simS + col * 528 + r0 * 2) = hv;
      }
    }
  }
  __syncthreads();
  // ---- P6: softmax + aggregate + residual + instance norm -> q04 ----
  float ffv[4];
#pragma unroll
  for (int si = 0; si < 4; ++si) {
    int s = h * 4 + si;
    float sv[5], vp[5];
#pragma unroll
    for (int j = 0; j < 5; ++j) {
      int sj = s * 5 + j;
      sv[j] = bf2f(*(const short*)(simS + sj * 528 + 2 * ch));
      vp[j] = bf2f(*(const short*)(vpeB + ((sj * 512 + 2 * ch) ^ ((sj & 7) << 4))));
    }
    float mx = sv[0];
#pragma unroll
    for (int j = 1; j < 5; ++j) mx = fmaxf(mx, sv[j]);
    float ssum = 0.f;
#pragma unroll
    for (int j = 0; j < 5; ++j) { sv[j] = expf(sv[j] - mx); ssum += sv[j]; }
    float inv = 1.f / ssum;
    float agg = 0.f;
#pragma unroll
    for (int j = 0; j < 5; ++j) agg += (sv[j] * inv) * vp[j];
    ffv[si] = agg + sfeat[((size_t)b * Fc + ch) * Nc + (n0 + s)];
  }
  {
    float rv[8];
#pragma unroll
    for (int si = 0; si < 4; ++si) { rv[si] = ffv[si]; rv[4 + si] = ffv[si] * ffv[si]; }
#pragma unroll
    for (int m = 1; m < 64; m <<= 1)
#pragma unroll
      for (int i2 = 0; i2 < 8; ++i2) rv[i2] += __shfl_xor(rv[i2], m);
    if ((t & 63) == 0)
#pragma unroll
      for (int i2 = 0; i2 < 8; ++i2) redf[w * 8 + i2] = rv[i2];
    __syncthreads();
#pragma unroll
    for (int si = 0; si < 4; ++si) {
      int s = h * 4 + si;
      float S = 0.f, Q = 0.f;
#pragma unroll
      for (int q2 = 0; q2 < 4; ++q2) {
        S += redf[(h * 4 + q2) * 8 + si];
        Q += redf[(h * 4 + q2) * 8 + 4 + si];
      }
      float mu = S * (1.f / 256.f);
      float var = Q * (1.f / 256.f) - mu * mu;
      q04[s * 256 + ch] = (ffv[si] - mu) / sqrtf(var + 1e-5f);
    }
  }
  __syncthreads();
  // ---- P7: feaB cols 0-7 from q04; zero cols 8-15 ----
  for (int z = t; z < 16 * 256; z += 512) {
    int col = z >> 8, k = z & 255;
    short val = (col < 8) ? f2bf(q04[col * 256 + k]) : (short)0;
    *(short*)(feaB + ((col * 512 + 2 * k) ^ ((col & 7) << 4))) = val;
  }
  __syncthreads();
  // ---- P8: fea layer 1 -> feaH ----
  {
    f32x4 acc[2];
#pragma unroll
    for (int i = 0; i < 2; ++i) acc[i] = (f32x4){0,0,0,0};
    for (int kk = 0; kk < 8; ++kk) {
      short8b b0 = *(const short8b*)(feaB + ((lr * 512 + kk * 64 + lg * 16) ^ ((lr & 7) << 4)));
#pragma unroll
      for (int i = 0; i < 2; ++i) {
        short8b a = *(const short8b*)(fw1f + (((size_t)((w * 2 + i) * 8 + kk)) * 64 + l) * 8);
        acc[i] = __builtin_amdgcn_mfma_f32_16x16x32_bf16(a, b0, acc[i], 0, 0, 0);
      }
    }
#pragma unroll
    for (int i = 0; i < 2; ++i) {
      int r0 = (w * 2 + i) * 16 + lg * 4;
      float4 gg = *(const float4*)(fg1 + r0), bs = *(const float4*)(fb1 + r0);
      int cx = (lr & 7) << 4;
      ushort4 hv;
      hv.x = (unsigned short)f2bf(fmaxf(gg.x * acc[i][0] + bs.x, 0.f));
      hv.y = (unsigned short)f2bf(fmaxf(gg.y * acc[i][1] + bs.y, 0.f));
      hv.z = (unsigned short)f2bf(fmaxf(gg.z * acc[i][2] + bs.z, 0.f));
      hv.w = (unsigned short)f2bf(fmaxf(gg.w * acc[i][3] + bs.w, 0.f));
      *(ushort4*)(feaH + ((lr * 512 + r0 * 2) ^ cx)) = hv;
    }
  }
  __syncthreads();
  // ---- P9: fea layer 2 -> y2F cols 0-7 ----
  {
    f32x4 acc[2];
#pragma unroll
    for (int i = 0; i < 2; ++i) acc[i] = (f32x4){0,0,0,0};
    for (int kk = 0; kk < 8; ++kk) {
      short8b b0 = *(const short8b*)(feaH + ((lr * 512 + kk * 64 + lg * 16) ^ ((lr & 7) << 4)));
#pragma unroll
      for (int i = 0; i < 2; ++i) {
        short8b a = *(const short8b*)(fw2f + (((size_t)((w * 2 + i) * 8 + kk)) * 64 + l) * 8);
        acc[i] = __builtin_amdgcn_mfma_f32_16x16x32_bf16(a, b0, acc[i], 0, 0, 0);
      }
    }
#pragma unroll
    for (int i = 0; i < 2; ++i) {
      if (lr < 8) {
        int r0 = (w * 2 + i) * 16 + lg * 4;
        float4 bs = *(const float4*)(fb2v + r0);
        float4 v;
        v.x = acc[i][0] + bs.x; v.y = acc[i][1] + bs.y;
        v.z = acc[i][2] + bs.z; v.w = acc[i][3] + bs.w;
        *(float4*)(y2F + lr * 260 + r0) = v;
      }
    }
  }
  __syncthreads();
  // ---- P10: z = y2 + ffn; instance norm; out ----
  {
    float zv[4];
#pragma unroll
    for (int si = 0; si < 4; ++si) {
      int s = h * 4 + si;
      zv[si] = y2F[s * 260 + ch] + q04[s * 256 + ch];
    }
    float rv[8];
#pragma unroll
    for (int si = 0; si < 4; ++si) { rv[si] = zv[si]; rv[4 + si] = zv[si] * zv[si]; }
#pragma unroll
    for (int m = 1; m < 64; m <<= 1)
#pragma unroll
      for (int i2 = 0; i2 < 8; ++i2) rv[i2] += __shfl_xor(rv[i2], m);
    if ((t & 63) == 0)
#pragma unroll
      for (int i2 = 0; i2 < 8; ++i2) redf[w * 8 + i2] = rv[i2];
    __syncthreads();
#pragma unroll
    for (int si = 0; si < 4; ++si) {
      int s = h * 4 + si;
      float S = 0.f, Q = 0.f;
#pragma unroll
      for (int q2 = 0; q2 < 4; ++q2) {
        S += redf[(h * 4 + q2) * 8 + si];
        Q += redf[(h * 4 + q2) * 8 + 4 + si];
      }
      float mu = S * (1.f / 256.f);
      float var = Q * (1.f / 256.f) - mu * mu;
      yout[((size_t)(tau0 + s)) * 256 + ch] = (zv[si] - mu) / sqrtf(var + 1e-5f);
    }
  }
}

// ---- PointSIFT octant-NN: ONE WAVE PER POINT, zero barriers ----
__global__ __launch_bounds__(256) void sift_idx_kernel(const float* __restrict__ sxyz,
                                                       int* __restrict__ sidx) {
  int wv = threadIdx.x >> 6, l = threadIdx.x & 63;
  int pt = blockIdx.x * 4 + wv;
  int b = pt / Nc, i = pt % Nc;
  const float* x = sxyz + (size_t)b * Nc * 3;
  float xi0 = x[3 * i], xi1 = x[3 * i + 1], xi2 = x[3 * i + 2];
  unsigned long long k8[8];
#pragma unroll
  for (int o = 0; o < 8; ++o) k8[o] = ~0ULL;
  for (int q = 0; q < 16; ++q) {
    int j = q * 64 + l;
    float dx = x[3 * j] - xi0, dy = x[3 * j + 1] - xi1, dz = x[3 * j + 2] - xi2;
    float d2 = dx * dx + dy * dy + dz * dz;
    bool ok = (d2 <= 0.25f) && (d2 > 0.f);
    int oc = (dx > 0.f ? 4 : 0) + (dy > 0.f ? 2 : 0) + (dz > 0.f ? 1 : 0);
    unsigned long long c = ((unsigned long long)__float_as_uint(d2) << 32) | (unsigned)j;
#pragma unroll
    for (int o = 0; o < 8; ++o) {
      unsigned long long cc = (ok && oc == o) ? c : ~0ULL;
      k8[o] = umin64(k8[o], cc);
    }
  }
#pragma unroll
  for (int m = 1; m < 64; m <<= 1)
#pragma unroll
    for (int o = 0; o < 8; ++o) k8[o] = umin64(k8[o], __shfl_xor(k8[o], m));
  if (l < 8) {
    unsigned long long r = ~0ULL;
#pragma unroll
    for (int o = 0; o < 8; ++o)
      if (l == o) r = k8[o];
    int j = (r == ~0ULL) ? i : (int)(unsigned)r;
    sidx[(((size_t)b * Nc + i) << 3) + l] = j;
  }
}

// ---- fused PointSIFT OE: 3 (1,2)-convs via MFMA, 8 points/block, 512 threads ----
__global__ __launch_bounds__(512, 4) void sift_oe_kernel(
    const float* __restrict__ sxyz, const int* __restrict__ sidx,
    const float* __restrict__ yin,
    const short* __restrict__ w1f, const float* __restrict__ g1, const float* __restrict__ b1,
    const short* __restrict__ w2f, const float* __restrict__ g2, const float* __restrict__ b2,
    const short* __restrict__ w3f, const float* __restrict__ g3, const float* __restrict__ b3,
    float* __restrict__ yout) {
  __shared__ __align__(16) char smem[51200];
  char* B1 = smem;
  char* B2 = smem + 34816;
  char* B3 = smem;
  __shared__ int js[8][8];
  int t = threadIdx.x;
  int i0 = blockIdx.x * 8;
  int b = i0 / Nc, nb = i0 % Nc;
  int h = t >> 8, ch = t & 255;
  if (t < 64) js[t >> 3][t & 7] = sidx[(((size_t)b * Nc + nb + (t >> 3)) << 3) + (t & 7)];
  for (int z = t; z < 32 * 26; z += 512) {
    int col = z / 26, k = 518 + z % 26;
    *(short*)(B1 + ((col * 1088 + 2 * k) ^ ((col & 7) << 4))) = 0;
  }
  __syncthreads();
  for (int si = 0; si < 4; ++si) {
    int s = h * 4 + si;
    int ii = nb + s;
#pragma unroll
    for (int p = 0; p < 4; ++p) {
      int ja = js[s][2 * p], jb = js[s][2 * p + 1];
      int col = s * 4 + p; int cx = (col & 7) << 4;
      float va = yin[((size_t)b * Nc + ja) * 256 + ch];
      float vb = yin[((size_t)b * Nc + jb) * 256 + ch];
      unsigned int packed = (unsigned int)(unsigned short)f2bf(va) |
                            ((unsigned int)(unsigned short)f2bf(vb) << 16);
      *(unsigned int*)(B1 + ((col * 1088 + 12 + 4 * ch) ^ cx)) = packed;
      if (ch < 3) {
        float base = sxyz[((size_t)b * Nc + ii) * 3 + ch];
        float ga = sxyz[((size_t)b * Nc + ja) * 3 + ch] - base;
        float gb = sxyz[((size_t)b * Nc + jb) * 3 + ch] - base;
        unsigned int pg = (unsigned int)(unsigned short)f2bf(ga) |
                          ((unsigned int)(unsigned short)f2bf(gb) << 16);
        *(unsigned int*)(B1 + ((col * 1088 + 4 * ch) ^ cx)) = pg;
      }
    }
  }
  __syncthreads();
  int l = t & 63, w = t >> 6, lg = l >> 4, lr = l & 15;
  {
    f32x4 acc[2][2];
#pragma unroll
    for (int i = 0; i < 2; ++i) { acc[i][0] = (f32x4){0,0,0,0}; acc[i][1] = (f32x4){0,0,0,0}; }
    for (int kk = 0; kk < 17; ++kk) {
      short8b b0[2];
#pragma unroll
      for (int ct = 0; ct < 2; ++ct) {
        int col = ct * 16 + lr;
        b0[ct] = *(const short8b*)(B1 + ((col * 1088 + kk * 64 + lg * 16) ^ ((col & 7) << 4)));
      }
#pragma unroll
      for (int i = 0; i < 2; ++i) {
        short8b a = *(const short8b*)(w1f + (((size_t)((w * 2 + i) * 17 + kk)) * 64 + l) * 8);
#pragma unroll
        for (int ct = 0; ct < 2; ++ct)
          acc[i][ct] = __builtin_amdgcn_mfma_f32_16x16x32_bf16(a, b0[ct], acc[i][ct], 0, 0, 0);
      }
    }
    __syncthreads();
#pragma unroll
    for (int i = 0; i < 2; ++i) {
      int r0 = (w * 2 + i) * 16 + lg * 4;
      float4 gg = *(const float4*)(g1 + r0), bs = *(const float4*)(b1 + r0);
#pragma unroll
      for (int ct = 0; ct < 2; ++ct) {
        int col = ct * 16 + lr;
        int s = col >> 2, p = col & 3, p2 = p >> 1, tp = p & 1;
        int col2 = s * 2 + p2; int cx2 = (col2 & 7) << 4;
        *(short*)(B2 + ((col2 * 1024 + (2 * r0 + tp) * 2) ^ cx2)) =
            f2bf(fmaxf(gg.x * acc[i][ct][0] + bs.x, 0.f));
        *(short*)(B2 + ((col2 * 1024 + (2 * (r0 + 1) + tp) * 2) ^ cx2)) =
            f2bf(fmaxf(gg.y * acc[i][ct][1] + bs.y, 0.f));
        *(short*)(B2 + ((col2 * 1024 + (2 * (r0 + 2) + tp) * 2) ^ cx2)) =
            f2bf(fmaxf(gg.z * acc[i][ct][2] + bs.z, 0.f));
        *(short*)(B2 + ((col2 * 1024 + (2 * (r0 + 3) + tp) * 2) ^ cx2)) =
            f2bf(fmaxf(gg.w * acc[i][ct][3] + bs.w, 0.f));
      }
    }
  }
  __syncthreads();
  {
    f32x4 acc[2];
#pragma unroll
    for (int i = 0; i < 2; ++i) acc[i] = (f32x4){0,0,0,0};
    for (int kk = 0; kk < 16; ++kk) {
      short8b b0 = *(const short8b*)(B2 + ((lr * 1024 + kk * 64 + lg * 16) ^ ((lr & 7) << 4)));
#pragma unroll
      for (int i = 0; i < 2; ++i) {
        short8b a = *(const short8b*)(w2f + (((size_t)((w * 2 + i) * 16 + kk)) * 64 + l) * 8);
        acc[i] = __builtin_amdgcn_mfma_f32_16x16x32_bf16(a, b0, acc[i], 0, 0, 0);
      }
    }
    __syncthreads();
    int s = lr >> 1, tp = lr & 1;
    int col3 = s; int cx3 = (col3 & 7) << 4;
#pragma unroll
    for (int i = 0; i < 2; ++i) {
      int r0 = (w * 2 + i) * 16 + lg * 4;
      float4 gg = *(const float4*)(g2 + r0), bs = *(const float4*)(b2 + r0);
      *(short*)(B3 + ((col3 * 1024 + (2 * r0 + tp) * 2) ^ cx3)) =
          f2bf(fmaxf(gg.x * acc[i][0] + bs.x, 0.f));
      *(short*)(B3 + ((col3 * 1024 + (2 * (r0 + 1) + tp) * 2) ^ cx3)) =
          f2bf(fmaxf(gg.y * acc[i][1] + bs.y, 0.f));
      *(short*)(B3 + ((col3 * 1024 + (2 * (r0 + 2) + tp) * 2) ^ cx3)) =
          f2bf(fmaxf(gg.z * acc[i][2] + bs.z, 0.f));
      *(short*)(B3 + ((col3 * 1024 + (2 * (r0 + 3) + tp) * 2) ^ cx3)) =
          f2bf(fmaxf(gg.w * acc[i][3] + bs.w, 0.f));
    }
  }
  __syncthreads();
  {
    f32x4 acc[2];
#pragma unroll
    for (int i = 0; i < 2; ++i) acc[i] = (f32x4){0,0,0,0};
    for (int kk = 0; kk < 16; ++kk) {
      short8b b0 = *(const short8b*)(B3 + ((lr * 1024 + kk * 64 + lg * 16) ^ ((lr & 7) << 4)));
#pragma unroll
      for (int i = 0; i < 2; ++i) {
        short8b a = *(const short8b*)(w3f + (((size_t)((w * 2 + i) * 16 + kk)) * 64 + l) * 8);
        acc[i] = __builtin_amdgcn_mfma_f32_16x16x32_bf16(a, b0, acc[i], 0, 0, 0);
      }
    }
#pragma unroll
    for (int i = 0; i < 2; ++i) {
      if (lr < 8) {
        int s = lr;
        int r0 = (w * 2 + i) * 16 + lg * 4;
        float4 gg = *(const float4*)(g3 + r0), bs = *(const float4*)(b3 + r0);
        float4 yv = *(const float4*)(yin + ((size_t)(i0 + s)) * 256 + r0);
        float4 ov;
        ov.x = yv.x + fmaxf(gg.x * acc[i][0] + bs.x, 0.f);
        ov.y = yv.y + fmaxf(gg.y * acc[i][1] + bs.y, 0.f);
        ov.z = yv.z + fmaxf(gg.z * acc[i][2] + bs.z, 0.f);
        ov.w = yv.w + fmaxf(gg.w * acc[i][3] + bs.w, 0.f);
        *(float4*)(yout + ((size_t)(i0 + s)) * 256 + r0) = ov;
      }
    }
  }
}

// ---- final transpose (B,N,C) -> (B,C,N), LDS-tiled, coalesced both sides ----
__global__ __launch_bounds__(256) void transpose_kernel(const float* __restrict__ yin,
                                                        float* __restrict__ out) {
  __shared__ float tile[64][65];
  int bid = blockIdx.x;
  int b = bid >> 6;
  int tl = bid & 63;
  int n0 = (tl >> 2) * 64;
  int c0 = (tl & 3) * 64;
  int tx = threadIdx.x & 63, ty = threadIdx.x >> 6;
#pragma unroll
  for (int r = 0; r < 16; ++r) {
    int i = r * 4 + ty;
    tile[i][tx] = yin[((size_t)b * Nc + n0 + i) * 256 + c0 + tx];
  }
  __syncthreads();
#pragma unroll
  for (int r = 0; r < 16; ++r) {
    int j = r * 4 + ty;
    out[((size_t)b * Fc + c0 + j) * Nc + n0 + tx] = tile[tx][j];
  }
}

extern "C" void kernel_launch(void* const* d_in, const int* in_sizes, int n_in,
                              void* d_out, int out_size, void* d_ws, size_t ws_size,
                              hipStream_t stream) {
  (void)in_sizes; (void)n_in; (void)out_size; (void)ws_size;
  const float* tfeat = (const float*)d_in[0];
  const float* sfeat = (const float*)d_in[1];
  const float* txyz  = (const float*)d_in[2];
  const float* sxyz  = (const float*)d_in[3];
  const float* tbc   = (const float*)d_in[4];
  const float* sbc   = (const float*)d_in[5];
  const float* mw1 = (const float*)d_in[6];
  const float* mg1 = (const float*)d_in[7];
  const float* mb1 = (const float*)d_in[8];
  const float* mw2 = (const float*)d_in[9];
  const float* mg2 = (const float*)d_in[10];
  const float* mb2 = (const float*)d_in[11];
  const float* mw3 = (const float*)d_in[12];
  const float* mg3 = (const float*)d_in[13];
  const float* mb3 = (const float*)d_in[14];
  const float* fw1 = (const float*)d_in[15];
  const float* fg1 = (const float*)d_in[16];
  const float* fb1 = (const float*)d_in[17];
  const float* fw2 = (const float*)d_in[18];
  const float* fb2 = (const float*)d_in[19];
  const float* wqkv = (const float*)d_in[20];
  const float* pw1 = (const float*)d_in[21];
  const float* pb1 = (const float*)d_in[22];
  const float* pw2 = (const float*)d_in[23];
  const float* pb2 = (const float*)d_in[24];
  const float* aw1 = (const float*)d_in[25];
  const float* ab1 = (const float*)d_in[26];
  const float* aw2 = (const float*)d_in[27];
  const float* ab2 = (const float*)d_in[28];
  const float* o1w1 = (const float*)d_in[29];
  const float* o1g1 = (const float*)d_in[30];
  const float* o1b1 = (const float*)d_in[31];
  const float* o1w2 = (const float*)d_in[32];
  const float* o1g2 = (const float*)d_in[33];
  const float* o1b2 = (const float*)d_in[34];
  const float* o1w3 = (const float*)d_in[35];
  const float* o1g3 = (const float*)d_in[36];
  const float* o1b3 = (const float*)d_in[37];
  const float* o2w1 = (const float*)d_in[38];
  const float* o2g1 = (const float*)d_in[39];
  const float* o2b1 = (const float*)d_in[40];
  const float* o2w2 = (const float*)d_in[41];
  const float* o2g2 = (const float*)d_in[42];
  const float* o2b2 = (const float*)d_in[43];
  const float* o2w3 = (const float*)d_in[44];
  const float* o2g3 = (const float*)d_in[45];
  const float* o2b3 = (const float*)d_in[46];

  // workspace layout (identical to R10; hbufS region now only used as ybuf2)
  float* ws = (float*)d_ws;
  float* sd   = ws;
  float* td   = sd + 65536;
  float* sscf = td + 32768;
  float* tscf = sscf + 12288;
  int*   idxs = (int*)(tscf + 6144);
  int*   sidx = idxs + 16384;
  float* yws  = (float*)(sidx + 32768);
  short* sb   = (short*)(yws + 1048576);
  short* mw1f  = sb + 5242880;
  short* mw2f  = mw1f + 73728;
  short* mw3f  = mw2f + 65536;
  short* aqf   = mw3f + 65536;
  short* akpef = aqf + 65536;
  short* avpef = akpef + 81920;
  short* aw1f  = avpef + 81920;
  short* aw2f  = aw1f + 262144;
  short* fw1f  = aw2f + 262144;
  short* fw2f  = fw1f + 65536;
  short* o1w1f = fw2f + 65536;
  short* o1w2f = o1w1f + 139264;
  short* o1w3f = o1w2f + 131072;
  short* o2w1f = o1w3f + 131072;
  short* o2w2f = o2w1f + 139264;
  short* o2w3f = o2w2f + 131072;
  float* ybuf2 = (float*)sb;

  WSrcs srcs;
  srcs.p[0] = mw1;  srcs.p[1] = mw2;  srcs.p[2] = mw3;  srcs.p[3] = wqkv;
  srcs.p[4] = wqkv; srcs.p[5] = wqkv; srcs.p[6] = aw1;  srcs.p[7] = aw2;
  srcs.p[8] = fw1;  srcs.p[9] = fw2;  srcs.p[10] = o1w1; srcs.p[11] = o1w2;
  srcs.p[12] = o1w3; srcs.p[13] = o2w1; srcs.p[14] = o2w2; srcs.p[15] = o2w3;
  wconv_all<<<7392, 256, 0, stream>>>(srcs, pw2, mw1f);

  scf_kernel<<<Bc, 256, 0, stream>>>(sxyz, sscf, Nc);
  scf_kernel<<<Bc, 256, 0, stream>>>(txyz, tscf, Mc);
  knn_kernel<Nc><<<Bc * Nc / 4, 256, 0, stream>>>(sxyz, sd);
  knn_kernel<Mc><<<Bc * Mc / 4, 256, 0, stream>>>(txyz, td);
  select_kernel<<<Bc * Nc / 4, 256, 0, stream>>>(tbc, sbc, txyz, sxyz, sd, td, idxs);
  mlp_attn_kernel<<<Bc * Nc / 8, 512, 0, stream>>>(
      sfeat, tfeat, sscf, tscf, idxs,
      mw1f, mg1, mb1, mw2f, mg2, mb2, mw3f, mg3, mb3,
      sxyz, sbc, txyz, tbc,
      aqf, akpef, avpef, pw1, pb1, pb2,
      aw1f, ab1, aw2f, ab2,
      fw1f, fg1, fb1, fw2f, fb2, yws);
  sift_idx_kernel<<<Bc * Nc / 4, 256, 0, stream>>>(sxyz, sidx);
  sift_oe_kernel<<<Bc * Nc / 8, 512, 0, stream>>>(sxyz, sidx, yws,
                                                  o1w1f, o1g1, o1b1, o1w2f, o1g2, o1b2,
                                                  o1w3f, o1g3, o1b3, ybuf2);
  sift_oe_kernel<<<Bc * Nc / 8, 512, 0, stream>>>(sxyz, sidx, ybuf2,
                                                  o2w1f, o2g1, o2b1, o2w2f, o2g2, o2b2,
                                                  o2w3f, o2g3, o2b3, yws);
  transpose_kernel<<<256, 256, 0, stream>>>(yws, (float*)d_out);
}